// Round 1
// 932.359 us; speedup vs baseline: 1.0112x; 1.0112x over previous
//
#include <hip/hip_runtime.h>

typedef unsigned short u16;
typedef unsigned int   u32;
typedef unsigned long long u64;
typedef __attribute__((ext_vector_type(8))) __bf16 bf16x8;
typedef __attribute__((ext_vector_type(4))) float  f32x4;

#define TOK 8192
#define DIM 1024
#define NE  16
#define NF  4096
#define CAP 512

// ---------- helpers ----------
__device__ __forceinline__ u16 f2bf(float f) {
    u32 u = __float_as_uint(f);
    u32 r = (u + 0x7FFFu + ((u >> 16) & 1u)) >> 16;   // RNE
    return (u16)r;
}

__device__ __forceinline__ float gelu_tanh(float x) {
    float u = 0.7978845608028654f * (x + 0.044715f * x * x * x);
    float t = __expf(-2.f * fabsf(u));
    float th = (1.f - t) / (1.f + t);
    th = (u < 0.f) ? -th : th;
    return 0.5f * x * (1.f + th);
}

__device__ __forceinline__ void gld16(const void* g, void* l) {
    __builtin_amdgcn_global_load_lds(
        (const __attribute__((address_space(1))) void*)g,
        (__attribute__((address_space(3))) void*)l, 16, 0, 0);
}

// ---------- small kernels ----------
__global__ void moe_init(float* me_sums) {
    if (threadIdx.x < NE) me_sums[threadIdx.x] = 0.f;
}

__global__ void moe_wgT(const float* __restrict__ wg, float* __restrict__ wgT) {
    int i = blockIdx.x * 256 + threadIdx.x;     // 16384 elements
    int d = i >> 4, e = i & 15;
    wgT[(size_t)e * DIM + d] = wg[i];
}

// one thread per (token, expert); 256 thr = 16 tokens x 16 experts
__global__ void moe_gate(const float* __restrict__ x, const float* __restrict__ wgT,
                         int* __restrict__ eidx, float* __restrict__ gp,
                         float* __restrict__ me_sums) {
    __shared__ float lme[NE];
    const int tid = threadIdx.x;
    if (tid < NE) lme[tid] = 0.f;
    __syncthreads();
    const int tok = blockIdx.x * 16 + (tid >> 4);
    const int e   = tid & 15;
    const float4* xp = (const float4*)(x + (size_t)tok * DIM);
    const float4* wp = (const float4*)(wgT + (size_t)e * DIM);
    float acc = 0.f;
#pragma unroll 4
    for (int i = 0; i < DIM / 4; ++i) {
        float4 a = xp[i], b = wp[i];
        acc = fmaf(a.x, b.x, acc); acc = fmaf(a.y, b.y, acc);
        acc = fmaf(a.z, b.z, acc); acc = fmaf(a.w, b.w, acc);
    }
    // softmax across the 16-lane expert group
    float mx = acc;
    for (int off = 8; off; off >>= 1) mx = fmaxf(mx, __shfl_xor(mx, off, 16));
    float ex = __expf(acc - mx);
    float sum = ex;
    for (int off = 8; off; off >>= 1) sum += __shfl_xor(sum, off, 16);
    float p = ex / sum;
    atomicAdd(&lme[e], p);
    // argmax (first index on ties, matching jnp.argmax)
    float bv = acc; int bi = e;
    for (int off = 8; off; off >>= 1) {
        float ov = __shfl_xor(bv, off, 16);
        int   oi = __shfl_xor(bi, off, 16);
        if (ov > bv || (ov == bv && oi < bi)) { bv = ov; bi = oi; }
    }
    float pw = __shfl(p, bi, 16);
    if (e == 0) { eidx[tok] = bi; gp[tok] = pw; }
    __syncthreads();
    if (tid < 16) atomicAdd(&me_sums[tid], lme[tid]);
}

// single block, 1024 threads: ordered cumsum slot assignment + counts + l_aux
__global__ void moe_scan(const int* __restrict__ eidx, const float* __restrict__ me_sums,
                         int* __restrict__ slot, int* __restrict__ tos,
                         float* __restrict__ tail /* d_out + TOK*DIM */) {
    __shared__ int wcnt[16][16];
    __shared__ int base[16];
    const int tid = threadIdx.x, wid = tid >> 6, lane = tid & 63;
    if (tid < 16) base[tid] = 0;
    for (int i = tid; i < NE * CAP; i += 1024) tos[i] = -1;
    __syncthreads();
    const u64 below = ((u64)1 << lane) - 1;
    for (int chunk = 0; chunk < TOK / 1024; ++chunk) {
        int t = chunk * 1024 + tid;
        int e = eidx[t];
        int rank = 0;
#pragma unroll
        for (int ex = 0; ex < 16; ++ex) {
            u64 m = __ballot(e == ex);
            if (e == ex)    rank = __popcll(m & below);
            if (lane == ex) wcnt[wid][ex] = __popcll(m);
        }
        __syncthreads();
        int pre = base[e];
        for (int w = 0; w < wid; ++w) pre += wcnt[w][e];
        int s = pre + rank;
        slot[t] = s;
        if (s < CAP) tos[e * CAP + s] = t;
        __syncthreads();
        if (tid < 16) {
            int tot = 0;
            for (int w = 0; w < 16; ++w) tot += wcnt[w][tid];
            base[tid] += tot;
        }
        __syncthreads();
    }
    if (tid == 0) {
        float laux = 0.f;
        for (int e2 = 0; e2 < 16; ++e2) {
            float me = me_sums[e2] / (float)TOK;
            float ce = (float)base[e2] / (float)TOK;
            laux += me * ce;
        }
        tail[0] = laux * (float)NE;
    }
    if (tid < 16) tail[1 + tid] = (float)base[tid];
}

// one block per slot row: gather x[token] -> bf16 Xg[slot]
__global__ void moe_gather(const float* __restrict__ x, const int* __restrict__ tos,
                           u16* __restrict__ Xg) {
    const int s = blockIdx.x, tid = threadIdx.x;
    const int t = tos[s];
    float4 v = make_float4(0.f, 0.f, 0.f, 0.f);
    if (t >= 0) v = *(const float4*)(x + (size_t)t * DIM + tid * 4);
    u32 lo = (u32)f2bf(v.x) | ((u32)f2bf(v.y) << 16);
    u32 hi = (u32)f2bf(v.z) | ((u32)f2bf(v.w) << 16);
    *(uint2*)(Xg + (size_t)s * DIM + tid * 4) = make_uint2(lo, hi);
}

__global__ void moe_zero_dropped(const int* __restrict__ slot, float* __restrict__ out) {
    const int t = blockIdx.x;
    if (slot[t] < CAP) return;
    *(float4*)(out + (size_t)t * DIM + threadIdx.x * 4) = make_float4(0.f, 0.f, 0.f, 0.f);
}

// transpose+convert: src [E][R][C] f32 -> dst [E][C][R] bf16 (64x64 tiles)
__global__ void moe_convT(const float* __restrict__ src, u16* __restrict__ dst,
                          int R, int C) {
    __shared__ float tile[64][65];
    int b = blockIdx.x;
    const int tilesC = C >> 6, tilesR = R >> 6;
    int tc = b % tilesC; b /= tilesC;
    int tr = b % tilesR; int e = b / tilesR;
    const float* S = src + ((size_t)e * R + tr * 64) * C + tc * 64;
    const int tid = threadIdx.x;
    const int rr = tid >> 4, cc = (tid & 15) * 4;
#pragma unroll
    for (int i = 0; i < 4; ++i) {
        float4 v = *(const float4*)(S + (size_t)(rr + i * 16) * C + cc);
        tile[rr + i * 16][cc + 0] = v.x; tile[rr + i * 16][cc + 1] = v.y;
        tile[rr + i * 16][cc + 2] = v.z; tile[rr + i * 16][cc + 3] = v.w;
    }
    __syncthreads();
    const int c = tid >> 2, r0 = (tid & 3) * 16;
    u16 tmp[16];
#pragma unroll
    for (int k = 0; k < 16; ++k) tmp[k] = f2bf(tile[r0 + k][c]);
    u16* D = dst + ((size_t)e * C + tc * 64 + c) * R + tr * 64 + r0;
    uint4 w0 = make_uint4((u32)tmp[0] | ((u32)tmp[1] << 16), (u32)tmp[2] | ((u32)tmp[3] << 16),
                          (u32)tmp[4] | ((u32)tmp[5] << 16), (u32)tmp[6] | ((u32)tmp[7] << 16));
    uint4 w1 = make_uint4((u32)tmp[8] | ((u32)tmp[9] << 16), (u32)tmp[10] | ((u32)tmp[11] << 16),
                          (u32)tmp[12] | ((u32)tmp[13] << 16), (u32)tmp[14] | ((u32)tmp[15] << 16));
    *(uint4*)(D) = w0;
    *(uint4*)(D + 8) = w1;
}

// ---------- GEMM1: H = gelu(Xg @ w1 + b1), bf16 out ----------
// flat 1-D grid, expert-per-XCD swizzle: xcd = flat&7 owns experts {2*xcd, 2*xcd+1}.
// Per expert 128 tiles (4 bm x 32 bn), bm fastest so co-resident same-XCD blocks
// share B panels and the A panel (Xg, 1 MB) stays L2-hot.
// 128x128 tile, BK=32, double-buffered, XOR-swizzled LDS.
__global__ __launch_bounds__(256) void moe_gemm1(const u16* __restrict__ Xg,
                                                 const u16* __restrict__ W1t,
                                                 const float* __restrict__ b1,
                                                 u16* __restrict__ H) {
    __shared__ alignas(16) u16 Als[2][4096];
    __shared__ alignas(16) u16 Bls[2][4096];
    const int tid = threadIdx.x, wave = tid >> 6, lane = tid & 63;
    const int flat = blockIdx.x;            // 0..2047
    const int xcd  = flat & 7;
    const int slot = flat >> 3;             // 0..255
    const int e    = xcd * 2 + (slot >> 7); // 2 experts per XCD
    const int tile = slot & 127;            // 0..127
    const int bmL  = tile & 3;              // bm fastest: B-panel sharers co-resident
    const int bn   = tile >> 2;             // 0..31
    const int bm   = e * 4 + bmL;
    const int r4  = lane >> 2;
    const int gch = (lane & 3) ^ ((lane >> 3) & 3);   // swizzled chunk this lane fetches
    const u16* aS = Xg + (size_t)(bm * 128 + wave * 32 + r4) * DIM + gch * 8;
    const u16* bS = W1t + (size_t)e * NF * DIM
                  + (size_t)(bn * 128 + wave * 32 + r4) * DIM + gch * 8;
    u16* aD0 = &Als[0][wave * 1024]; u16* aD1 = &Als[1][wave * 1024];
    u16* bD0 = &Bls[0][wave * 1024]; u16* bD1 = &Bls[1][wave * 1024];
    f32x4 acc[4][4] = {};
    const int wm = wave & 1, wn = wave >> 1;
    const int fr = lane & 15, fq = lane >> 4;
    const int rdoff = fr * 32 + (fq ^ ((fr >> 1) & 3)) * 8;   // swizzled read offset

#define STAGE1(AD, BD, K) do { \
        gld16(aS + (K), AD); gld16(aS + (K) + 16 * DIM, (AD) + 512); \
        gld16(bS + (K), BD); gld16(bS + (K) + 16 * DIM, (BD) + 512); } while (0)
#define COMP1(AB, BB) do { \
        bf16x8 aF[4], bF[4]; \
        _Pragma("unroll") for (int i = 0; i < 4; ++i) \
            aF[i] = *(const bf16x8*)(const void*)((AB) + (wm * 64 + i * 16) * 32 + rdoff); \
        _Pragma("unroll") for (int j = 0; j < 4; ++j) \
            bF[j] = *(const bf16x8*)(const void*)((BB) + (wn * 64 + j * 16) * 32 + rdoff); \
        _Pragma("unroll") for (int i = 0; i < 4; ++i) \
        _Pragma("unroll") for (int j = 0; j < 4; ++j) \
            acc[i][j] = __builtin_amdgcn_mfma_f32_16x16x32_bf16(aF[i], bF[j], acc[i][j], 0, 0, 0); \
        } while (0)

    STAGE1(aD0, bD0, 0);
    for (int k0 = 0; k0 < DIM; k0 += 64) {
        __syncthreads();
        if (k0 + 32 < DIM) STAGE1(aD1, bD1, k0 + 32);
        COMP1(&Als[0][0], &Bls[0][0]);
        __syncthreads();
        if (k0 + 64 < DIM) STAGE1(aD0, bD0, k0 + 64);
        COMP1(&Als[1][0], &Bls[1][0]);
    }
#undef STAGE1
#undef COMP1

    const int mBase = bm * 128 + wm * 64;
    const int nBase = bn * 128 + wn * 64;
#pragma unroll
    for (int j = 0; j < 4; ++j) {
        const int f = nBase + j * 16 + fr;
        const float bias = b1[e * NF + f];
#pragma unroll
        for (int i = 0; i < 4; ++i) {
            const int m0 = mBase + i * 16 + fq * 4;
#pragma unroll
            for (int r = 0; r < 4; ++r) {
                float v = acc[i][j][r] + bias;
                H[(size_t)(m0 + r) * NF + f] = f2bf(gelu_tanh(v));
            }
        }
    }
}

// ---------- GEMM2: out[token] = gate * (H @ w2 + b2), scattered ----------
// Rebuilt as 128x128 tile (16 MFMA per BK=32 per wave, same as gemm1) with the
// same expert-per-XCD swizzle. Per expert 32 tiles (4 bm x 8 bn), 512 blocks
// total = all co-resident (2 blocks/CU). K=NF=4096 streamed double-buffered.
__global__ __launch_bounds__(256) void moe_gemm2(const u16* __restrict__ H,
                                                 const u16* __restrict__ W2t,
                                                 const float* __restrict__ b2,
                                                 const int* __restrict__ tos,
                                                 const float* __restrict__ gp,
                                                 float* __restrict__ out) {
    __shared__ alignas(16) u16 Als[2][4096];   // 128 x 32
    __shared__ alignas(16) u16 Bls[2][4096];   // 128 x 32
    const int tid = threadIdx.x, wave = tid >> 6, lane = tid & 63;
    const int flat = blockIdx.x;            // 0..511
    const int xcd  = flat & 7;
    const int slot = flat >> 3;             // 0..63
    const int e    = xcd * 2 + (slot >> 5); // 2 experts per XCD
    const int tile = slot & 31;             // 0..31
    const int bmL  = tile & 3;
    const int bn   = tile >> 2;             // 0..7
    const int bm   = e * 4 + bmL;
    const int r4  = lane >> 2;
    const int gch = (lane & 3) ^ ((lane >> 3) & 3);
    const u16* aS = H + (size_t)(bm * 128 + wave * 32 + r4) * NF + gch * 8;
    const u16* bS = W2t + (size_t)e * DIM * NF
                  + (size_t)(bn * 128 + wave * 32 + r4) * NF + gch * 8;
    u16* aD0 = &Als[0][wave * 1024]; u16* aD1 = &Als[1][wave * 1024];
    u16* bD0 = &Bls[0][wave * 1024]; u16* bD1 = &Bls[1][wave * 1024];
    f32x4 acc[4][4] = {};
    const int wm = wave & 1, wn = wave >> 1;
    const int fr = lane & 15, fq = lane >> 4;
    const int rdoff = fr * 32 + (fq ^ ((fr >> 1) & 3)) * 8;

#define STAGE2(AD, BD, K) do { \
        gld16(aS + (K), AD); gld16(aS + (K) + 16 * NF, (AD) + 512); \
        gld16(bS + (K), BD); gld16(bS + (K) + 16 * NF, (BD) + 512); } while (0)
#define COMP2(AB, BB) do { \
        bf16x8 aF[4], bF[4]; \
        _Pragma("unroll") for (int i = 0; i < 4; ++i) \
            aF[i] = *(const bf16x8*)(const void*)((AB) + (wm * 64 + i * 16) * 32 + rdoff); \
        _Pragma("unroll") for (int j = 0; j < 4; ++j) \
            bF[j] = *(const bf16x8*)(const void*)((BB) + (wn * 64 + j * 16) * 32 + rdoff); \
        _Pragma("unroll") for (int i = 0; i < 4; ++i) \
        _Pragma("unroll") for (int j = 0; j < 4; ++j) \
            acc[i][j] = __builtin_amdgcn_mfma_f32_16x16x32_bf16(aF[i], bF[j], acc[i][j], 0, 0, 0); \
        } while (0)

    STAGE2(aD0, bD0, 0);
    for (int k0 = 0; k0 < NF; k0 += 64) {
        __syncthreads();
        if (k0 + 32 < NF) STAGE2(aD1, bD1, k0 + 32);
        COMP2(&Als[0][0], &Bls[0][0]);
        __syncthreads();
        if (k0 + 64 < NF) STAGE2(aD0, bD0, k0 + 64);
        COMP2(&Als[1][0], &Bls[1][0]);
    }
#undef STAGE2
#undef COMP2

    const int mBase = bm * 128 + wm * 64;
    const int nBase = bn * 128 + wn * 64;
#pragma unroll
    for (int i = 0; i < 4; ++i) {
#pragma unroll
        for (int r = 0; r < 4; ++r) {
            const int m = mBase + i * 16 + fq * 4 + r;
            const int t = tos[m];
            if (t < 0) continue;
            const float g = gp[t];
#pragma unroll
            for (int j = 0; j < 4; ++j) {
                const int d = nBase + j * 16 + fr;
                out[(size_t)t * DIM + d] = g * (acc[i][j][r] + b2[e * DIM + d]);
            }
        }
    }
}

// ---------- launch ----------
extern "C" void kernel_launch(void* const* d_in, const int* in_sizes, int n_in,
                              void* d_out, int out_size, void* d_ws, size_t ws_size,
                              hipStream_t stream) {
    const float* x  = (const float*)d_in[0];
    const float* wg = (const float*)d_in[1];
    const float* w1 = (const float*)d_in[2];
    const float* b1 = (const float*)d_in[3];
    const float* w2 = (const float*)d_in[4];
    const float* b2 = (const float*)d_in[5];
    float* out = (float*)d_out;

    char* ws = (char*)d_ws;
    const size_t WBF_OFF = 0;                                   // 134,217,728 B (shared by w1/w2 bf16)
    const size_t XG_OFF  = WBF_OFF + (size_t)NE * NF * DIM * 2; // 16,777,216 B
    const size_t H_OFF   = XG_OFF + (size_t)TOK * DIM * 2;      // 67,108,864 B
    const size_t SM_OFF  = H_OFF + (size_t)TOK * NF * 2;
    u16* Wbf = (u16*)(ws + WBF_OFF);
    u16* Xg  = (u16*)(ws + XG_OFF);
    u16* H   = (u16*)(ws + H_OFF);
    int*   eidx = (int*)(ws + SM_OFF);                 // 32 KB
    float* gp   = (float*)(ws + SM_OFF + 32768);       // 32 KB
    int*   slot = (int*)(ws + SM_OFF + 65536);         // 32 KB
    int*   tos  = (int*)(ws + SM_OFF + 98304);         // 32 KB
    float* me   = (float*)(ws + SM_OFF + 131072);      // 64 B
    float* wgT  = (float*)(ws + SM_OFF + 131072 + 128);// 64 KB (16B aligned)

    float* tail = out + (size_t)TOK * DIM;             // [l_aux, exp_counts x16]

    moe_init<<<1, 64, 0, stream>>>(me);
    moe_wgT<<<64, 256, 0, stream>>>(wg, wgT);
    moe_gate<<<TOK / 16, 256, 0, stream>>>(x, wgT, eidx, gp, me);
    moe_scan<<<1, 1024, 0, stream>>>(eidx, me, slot, tos, tail);
    moe_gather<<<NE * CAP, 256, 0, stream>>>(x, tos, Xg);
    moe_zero_dropped<<<TOK, 256, 0, stream>>>(slot, out);
    moe_convT<<<NE * (DIM / 64) * (NF / 64), 256, 0, stream>>>(w1, Wbf, DIM, NF);
    moe_gemm1<<<2048, 256, 0, stream>>>(Xg, Wbf, b1, H);
    moe_convT<<<NE * (NF / 64) * (DIM / 64), 256, 0, stream>>>(w2, Wbf, NF, DIM);
    moe_gemm2<<<512, 256, 0, stream>>>(H, Wbf, b2, tos, gp, out);
}

// Round 3
// 929.402 us; speedup vs baseline: 1.0144x; 1.0032x over previous
//
#include <hip/hip_runtime.h>

typedef unsigned short u16;
typedef unsigned int   u32;
typedef unsigned long long u64;
typedef __attribute__((ext_vector_type(8))) __bf16 bf16x8;
typedef __attribute__((ext_vector_type(4))) float  f32x4;

#define TOK 8192
#define DIM 1024
#define NE  16
#define NF  4096
#define CAP 512

// ---------- helpers ----------
__device__ __forceinline__ u16 f2bf(float f) {
    u32 u = __float_as_uint(f);
    u32 r = (u + 0x7FFFu + ((u >> 16) & 1u)) >> 16;   // RNE
    return (u16)r;
}

__device__ __forceinline__ float gelu_tanh(float x) {
    float u = 0.7978845608028654f * (x + 0.044715f * x * x * x);
    float t = __expf(-2.f * fabsf(u));
    float th = (1.f - t) / (1.f + t);
    th = (u < 0.f) ? -th : th;
    return 0.5f * x * (1.f + th);
}

__device__ __forceinline__ void gld16(const void* g, void* l) {
    __builtin_amdgcn_global_load_lds(
        (const __attribute__((address_space(1))) void*)g,
        (__attribute__((address_space(3))) void*)l, 16, 0, 0);
}

// ---------- small kernels ----------
__global__ void moe_init(float* me_sums) {
    if (threadIdx.x < NE) me_sums[threadIdx.x] = 0.f;
}

__global__ void moe_wgT(const float* __restrict__ wg, float* __restrict__ wgT) {
    int i = blockIdx.x * 256 + threadIdx.x;     // 16384 elements
    int d = i >> 4, e = i & 15;
    wgT[(size_t)e * DIM + d] = wg[i];
}

// one thread per (token, expert); 256 thr = 16 tokens x 16 experts
__global__ void moe_gate(const float* __restrict__ x, const float* __restrict__ wgT,
                         int* __restrict__ eidx, float* __restrict__ gp,
                         float* __restrict__ me_sums) {
    __shared__ float lme[NE];
    const int tid = threadIdx.x;
    if (tid < NE) lme[tid] = 0.f;
    __syncthreads();
    const int tok = blockIdx.x * 16 + (tid >> 4);
    const int e   = tid & 15;
    const float4* xp = (const float4*)(x + (size_t)tok * DIM);
    const float4* wp = (const float4*)(wgT + (size_t)e * DIM);
    float acc = 0.f;
#pragma unroll 4
    for (int i = 0; i < DIM / 4; ++i) {
        float4 a = xp[i], b = wp[i];
        acc = fmaf(a.x, b.x, acc); acc = fmaf(a.y, b.y, acc);
        acc = fmaf(a.z, b.z, acc); acc = fmaf(a.w, b.w, acc);
    }
    // softmax across the 16-lane expert group
    float mx = acc;
    for (int off = 8; off; off >>= 1) mx = fmaxf(mx, __shfl_xor(mx, off, 16));
    float ex = __expf(acc - mx);
    float sum = ex;
    for (int off = 8; off; off >>= 1) sum += __shfl_xor(sum, off, 16);
    float p = ex / sum;
    atomicAdd(&lme[e], p);
    // argmax (first index on ties, matching jnp.argmax)
    float bv = acc; int bi = e;
    for (int off = 8; off; off >>= 1) {
        float ov = __shfl_xor(bv, off, 16);
        int   oi = __shfl_xor(bi, off, 16);
        if (ov > bv || (ov == bv && oi < bi)) { bv = ov; bi = oi; }
    }
    float pw = __shfl(p, bi, 16);
    if (e == 0) { eidx[tok] = bi; gp[tok] = pw; }
    __syncthreads();
    if (tid < 16) atomicAdd(&me_sums[tid], lme[tid]);
}

// single block, 1024 threads: ordered cumsum slot assignment + counts + l_aux
__global__ void moe_scan(const int* __restrict__ eidx, const float* __restrict__ me_sums,
                         int* __restrict__ slot, int* __restrict__ tos,
                         float* __restrict__ tail /* d_out + TOK*DIM */) {
    __shared__ int wcnt[16][16];
    __shared__ int base[16];
    const int tid = threadIdx.x, wid = tid >> 6, lane = tid & 63;
    if (tid < 16) base[tid] = 0;
    for (int i = tid; i < NE * CAP; i += 1024) tos[i] = -1;
    __syncthreads();
    const u64 below = ((u64)1 << lane) - 1;
    for (int chunk = 0; chunk < TOK / 1024; ++chunk) {
        int t = chunk * 1024 + tid;
        int e = eidx[t];
        int rank = 0;
#pragma unroll
        for (int ex = 0; ex < 16; ++ex) {
            u64 m = __ballot(e == ex);
            if (e == ex)    rank = __popcll(m & below);
            if (lane == ex) wcnt[wid][ex] = __popcll(m);
        }
        __syncthreads();
        int pre = base[e];
        for (int w = 0; w < wid; ++w) pre += wcnt[w][e];
        int s = pre + rank;
        slot[t] = s;
        if (s < CAP) tos[e * CAP + s] = t;
        __syncthreads();
        if (tid < 16) {
            int tot = 0;
            for (int w = 0; w < 16; ++w) tot += wcnt[w][tid];
            base[tid] += tot;
        }
        __syncthreads();
    }
    if (tid == 0) {
        float laux = 0.f;
        for (int e2 = 0; e2 < 16; ++e2) {
            float me = me_sums[e2] / (float)TOK;
            float ce = (float)base[e2] / (float)TOK;
            laux += me * ce;
        }
        tail[0] = laux * (float)NE;
    }
    if (tid < 16) tail[1 + tid] = (float)base[tid];
}

// one block per slot row: gather x[token] -> bf16 Xg[slot]
__global__ void moe_gather(const float* __restrict__ x, const int* __restrict__ tos,
                           u16* __restrict__ Xg) {
    const int s = blockIdx.x, tid = threadIdx.x;
    const int t = tos[s];
    float4 v = make_float4(0.f, 0.f, 0.f, 0.f);
    if (t >= 0) v = *(const float4*)(x + (size_t)t * DIM + tid * 4);
    u32 lo = (u32)f2bf(v.x) | ((u32)f2bf(v.y) << 16);
    u32 hi = (u32)f2bf(v.z) | ((u32)f2bf(v.w) << 16);
    *(uint2*)(Xg + (size_t)s * DIM + tid * 4) = make_uint2(lo, hi);
}

__global__ void moe_zero_dropped(const int* __restrict__ slot, float* __restrict__ out) {
    const int t = blockIdx.x;
    if (slot[t] < CAP) return;
    *(float4*)(out + (size_t)t * DIM + threadIdx.x * 4) = make_float4(0.f, 0.f, 0.f, 0.f);
}

// transpose+convert: src [E][R][C] f32 -> dst [E][C][R] bf16 (64x64 tiles)
__global__ void moe_convT(const float* __restrict__ src, u16* __restrict__ dst,
                          int R, int C) {
    __shared__ float tile[64][65];
    int b = blockIdx.x;
    const int tilesC = C >> 6, tilesR = R >> 6;
    int tc = b % tilesC; b /= tilesC;
    int tr = b % tilesR; int e = b / tilesR;
    const float* S = src + ((size_t)e * R + tr * 64) * C + tc * 64;
    const int tid = threadIdx.x;
    const int rr = tid >> 4, cc = (tid & 15) * 4;
#pragma unroll
    for (int i = 0; i < 4; ++i) {
        float4 v = *(const float4*)(S + (size_t)(rr + i * 16) * C + cc);
        tile[rr + i * 16][cc + 0] = v.x; tile[rr + i * 16][cc + 1] = v.y;
        tile[rr + i * 16][cc + 2] = v.z; tile[rr + i * 16][cc + 3] = v.w;
    }
    __syncthreads();
    const int c = tid >> 2, r0 = (tid & 3) * 16;
    u16 tmp[16];
#pragma unroll
    for (int k = 0; k < 16; ++k) tmp[k] = f2bf(tile[r0 + k][c]);
    u16* D = dst + ((size_t)e * C + tc * 64 + c) * R + tr * 64 + r0;
    uint4 w0 = make_uint4((u32)tmp[0] | ((u32)tmp[1] << 16), (u32)tmp[2] | ((u32)tmp[3] << 16),
                          (u32)tmp[4] | ((u32)tmp[5] << 16), (u32)tmp[6] | ((u32)tmp[7] << 16));
    uint4 w1 = make_uint4((u32)tmp[8] | ((u32)tmp[9] << 16), (u32)tmp[10] | ((u32)tmp[11] << 16),
                          (u32)tmp[12] | ((u32)tmp[13] << 16), (u32)tmp[14] | ((u32)tmp[15] << 16));
    *(uint4*)(D) = w0;
    *(uint4*)(D + 8) = w1;
}

// ---------- GEMM1: H = gelu(Xg @ w1 + b1), bf16 out ----------
// 256x256 tile, BK=32, 8 waves (2Mx4N), 3-buffer LDS pipeline with counted
// vmcnt crossing raw s_barriers (never drains to 0 in steady state).
// Per wave per K-tile: 32 MFMA in two setprio-wrapped clusters of 16.
// Expert-per-XCD: xcd = flat&7 owns experts {2*xcd, 2*xcd+1}; 32 tiles/expert
// = exactly one residency round (1 block/CU, 96 KB LDS).
__global__ __launch_bounds__(512, 2) void moe_gemm1(const u16* __restrict__ Xg,
                                                    const u16* __restrict__ W1t,
                                                    const float* __restrict__ b1,
                                                    u16* __restrict__ H) {
    __shared__ alignas(16) u16 Als[3][8192];   // 3 x (256 rows x 32k) = 48 KB
    __shared__ alignas(16) u16 Bls[3][8192];   // 3 x (256 rows x 32k) = 48 KB
    const int tid = threadIdx.x, wave = tid >> 6, lane = tid & 63;
    const int flat = blockIdx.x;            // 0..511
    const int xcd  = flat & 7;
    const int slot = flat >> 3;             // 0..63
    const int e    = xcd * 2 + (slot >> 5); // 2 experts per XCD
    const int tile = slot & 31;             // 0..31
    const int bm   = tile & 1;              // 2 m-tiles (bm fastest)
    const int bn   = tile >> 1;             // 0..15
    const int r4   = lane >> 2;
    const int gch  = (lane & 3) ^ ((lane >> 3) & 3);   // source chunk pre-swizzle
    const u16* aSrc = Xg + (size_t)(e * 512 + bm * 256 + wave * 16 + r4) * DIM + gch * 8;
    const u16* bSrc = W1t + (size_t)e * NF * DIM
                    + (size_t)(bn * 256 + wave * 16 + r4) * DIM + gch * 8;
    const int wm = wave & 1, wn = wave >> 1;           // 2M x 4N wave grid
    const int fr = lane & 15, fq = lane >> 4;
    const int rdoff = fr * 32 + (fq ^ ((fr >> 1) & 3)) * 8;  // swizzled read offset

    f32x4 acc[2][4][4] = {};

#define STAGE1(P, T) do { \
        const int ko = (T) * 32; \
        u16* ad = &Als[P][wave * 512]; \
        u16* bd = &Bls[P][wave * 512]; \
        gld16(aSrc + ko, ad); \
        gld16(aSrc + 128 * DIM + ko, ad + 4096); \
        gld16(bSrc + ko, bd); \
        gld16(bSrc + 128 * DIM + ko, bd + 4096); } while (0)

    const int NT = DIM / 32;               // 32 K-tiles
    STAGE1(0, 0);
    STAGE1(1, 1);
    int c = 0;
    for (int t = 0; t < NT; ++t) {
        // tile t landed (per-wave), tiles t+1/t+2 stay in flight across barrier
        if (t < NT - 1) { asm volatile("s_waitcnt vmcnt(4)" ::: "memory"); }
        else            { asm volatile("s_waitcnt vmcnt(0)" ::: "memory"); }
        __builtin_amdgcn_sched_barrier(0);
        __builtin_amdgcn_s_barrier();
        __builtin_amdgcn_sched_barrier(0);
        const u16* Ab = &Als[c][0];
        const u16* Bb = &Bls[c][0];
        bf16x8 bF[4], aF[4];
#pragma unroll
        for (int j = 0; j < 4; ++j)
            bF[j] = *(const bf16x8*)(const void*)(Bb + (wn * 64 + j * 16) * 32 + rdoff);
#pragma unroll
        for (int i = 0; i < 4; ++i)
            aF[i] = *(const bf16x8*)(const void*)(Ab + (wm * 128 + i * 16) * 32 + rdoff);
        if (t + 2 < NT) {
            const int p = (c + 2 >= 3) ? (c - 1) : (c + 2);  // (t+2)%3
            STAGE1(p, t + 2);
        }
        __builtin_amdgcn_sched_barrier(0);
        __builtin_amdgcn_s_setprio(1);
#pragma unroll
        for (int i = 0; i < 4; ++i)
#pragma unroll
            for (int j = 0; j < 4; ++j)
                acc[0][i][j] = __builtin_amdgcn_mfma_f32_16x16x32_bf16(aF[i], bF[j], acc[0][i][j], 0, 0, 0);
        __builtin_amdgcn_s_setprio(0);
#pragma unroll
        for (int i = 0; i < 4; ++i)
            aF[i] = *(const bf16x8*)(const void*)(Ab + (wm * 128 + 64 + i * 16) * 32 + rdoff);
        __builtin_amdgcn_s_setprio(1);
#pragma unroll
        for (int i = 0; i < 4; ++i)
#pragma unroll
            for (int j = 0; j < 4; ++j)
                acc[1][i][j] = __builtin_amdgcn_mfma_f32_16x16x32_bf16(aF[i], bF[j], acc[1][i][j], 0, 0, 0);
        __builtin_amdgcn_s_setprio(0);
        c = (c == 2) ? 0 : c + 1;
    }
#undef STAGE1

    const int mBase = e * 512 + bm * 256 + wm * 128;
    const int nBase = bn * 256 + wn * 64;
#pragma unroll
    for (int j = 0; j < 4; ++j) {
        const int f = nBase + j * 16 + fr;
        const float bias = b1[e * NF + f];
#pragma unroll
        for (int q = 0; q < 2; ++q)
#pragma unroll
            for (int i = 0; i < 4; ++i) {
                const int m0 = mBase + q * 64 + i * 16 + fq * 4;
#pragma unroll
                for (int r = 0; r < 4; ++r) {
                    float v = acc[q][i][j][r] + bias;
                    H[(size_t)(m0 + r) * NF + f] = f2bf(gelu_tanh(v));
                }
            }
    }
}

// ---------- GEMM2: out[token] = gate * (H @ w2 + b2), scattered ----------
// 256x128 tile, BK=32, same 3-buffer counted-vmcnt pipeline (3 loads/tile).
// 16 tiles/expert x 16 experts = 256 blocks = one residency round (72 KB LDS).
__global__ __launch_bounds__(512, 2) void moe_gemm2(const u16* __restrict__ H,
                                                    const u16* __restrict__ W2t,
                                                    const float* __restrict__ b2,
                                                    const int* __restrict__ tos,
                                                    const float* __restrict__ gp,
                                                    float* __restrict__ out) {
    __shared__ alignas(16) u16 Als[3][8192];   // 3 x (256 x 32) = 48 KB
    __shared__ alignas(16) u16 Bls[3][4096];   // 3 x (128 x 32) = 24 KB
    const int tid = threadIdx.x, wave = tid >> 6, lane = tid & 63;
    const int flat = blockIdx.x;            // 0..255
    const int xcd  = flat & 7;
    const int slot = flat >> 3;             // 0..31
    const int e    = xcd * 2 + (slot >> 4); // 2 experts per XCD
    const int tile = slot & 15;             // 0..15
    const int bm   = tile & 1;
    const int bn   = tile >> 1;             // 0..7
    const int r4   = lane >> 2;
    const int gch  = (lane & 3) ^ ((lane >> 3) & 3);
    const u16* aSrc = H + (size_t)(e * 512 + bm * 256 + wave * 16 + r4) * NF + gch * 8;
    const u16* bSrc = W2t + (size_t)e * DIM * NF
                    + (size_t)(bn * 128 + wave * 16 + r4) * NF + gch * 8;
    const int wm = wave & 1, wn = wave >> 1;
    const int fr = lane & 15, fq = lane >> 4;
    const int rdoff = fr * 32 + (fq ^ ((fr >> 1) & 3)) * 8;

    f32x4 acc[2][4][2] = {};

#define STAGE2(P, T) do { \
        const int ko = (T) * 32; \
        u16* ad = &Als[P][wave * 512]; \
        u16* bd = &Bls[P][wave * 512]; \
        gld16(aSrc + ko, ad); \
        gld16(aSrc + (size_t)128 * NF + ko, ad + 4096); \
        gld16(bSrc + ko, bd); } while (0)

    const int NT = NF / 32;                // 128 K-tiles
    STAGE2(0, 0);
    STAGE2(1, 1);
    int c = 0;
    for (int t = 0; t < NT; ++t) {
        if (t < NT - 1) { asm volatile("s_waitcnt vmcnt(3)" ::: "memory"); }
        else            { asm volatile("s_waitcnt vmcnt(0)" ::: "memory"); }
        __builtin_amdgcn_sched_barrier(0);
        __builtin_amdgcn_s_barrier();
        __builtin_amdgcn_sched_barrier(0);
        const u16* Ab = &Als[c][0];
        const u16* Bb = &Bls[c][0];
        bf16x8 bF[2], aF[4];
#pragma unroll
        for (int j = 0; j < 2; ++j)
            bF[j] = *(const bf16x8*)(const void*)(Bb + (wn * 32 + j * 16) * 32 + rdoff);
#pragma unroll
        for (int i = 0; i < 4; ++i)
            aF[i] = *(const bf16x8*)(const void*)(Ab + (wm * 128 + i * 16) * 32 + rdoff);
        if (t + 2 < NT) {
            const int p = (c + 2 >= 3) ? (c - 1) : (c + 2);
            STAGE2(p, t + 2);
        }
        __builtin_amdgcn_sched_barrier(0);
        __builtin_amdgcn_s_setprio(1);
#pragma unroll
        for (int i = 0; i < 4; ++i)
#pragma unroll
            for (int j = 0; j < 2; ++j)
                acc[0][i][j] = __builtin_amdgcn_mfma_f32_16x16x32_bf16(aF[i], bF[j], acc[0][i][j], 0, 0, 0);
        __builtin_amdgcn_s_setprio(0);
#pragma unroll
        for (int i = 0; i < 4; ++i)
            aF[i] = *(const bf16x8*)(const void*)(Ab + (wm * 128 + 64 + i * 16) * 32 + rdoff);
        __builtin_amdgcn_s_setprio(1);
#pragma unroll
        for (int i = 0; i < 4; ++i)
#pragma unroll
            for (int j = 0; j < 2; ++j)
                acc[1][i][j] = __builtin_amdgcn_mfma_f32_16x16x32_bf16(aF[i], bF[j], acc[1][i][j], 0, 0, 0);
        __builtin_amdgcn_s_setprio(0);
        c = (c == 2) ? 0 : c + 1;
    }
#undef STAGE2

    const int mBase = e * 512 + bm * 256 + wm * 128;
    const int nBase = bn * 128 + wn * 32;
#pragma unroll
    for (int q = 0; q < 2; ++q)
#pragma unroll
        for (int i = 0; i < 4; ++i) {
#pragma unroll
            for (int r = 0; r < 4; ++r) {
                const int m = mBase + q * 64 + i * 16 + fq * 4 + r;
                const int t = tos[m];
                if (t < 0) continue;
                const float g = gp[t];
#pragma unroll
                for (int j = 0; j < 2; ++j) {
                    const int d = nBase + j * 16 + fr;
                    out[(size_t)t * DIM + d] = g * (acc[q][i][j][r] + b2[e * DIM + d]);
                }
            }
        }
}

// ---------- launch ----------
extern "C" void kernel_launch(void* const* d_in, const int* in_sizes, int n_in,
                              void* d_out, int out_size, void* d_ws, size_t ws_size,
                              hipStream_t stream) {
    const float* x  = (const float*)d_in[0];
    const float* wg = (const float*)d_in[1];
    const float* w1 = (const float*)d_in[2];
    const float* b1 = (const float*)d_in[3];
    const float* w2 = (const float*)d_in[4];
    const float* b2 = (const float*)d_in[5];
    float* out = (float*)d_out;

    char* ws = (char*)d_ws;
    const size_t WBF_OFF = 0;                                   // 134,217,728 B (shared by w1/w2 bf16)
    const size_t XG_OFF  = WBF_OFF + (size_t)NE * NF * DIM * 2; // 16,777,216 B
    const size_t H_OFF   = XG_OFF + (size_t)TOK * DIM * 2;      // 67,108,864 B
    const size_t SM_OFF  = H_OFF + (size_t)TOK * NF * 2;
    u16* Wbf = (u16*)(ws + WBF_OFF);
    u16* Xg  = (u16*)(ws + XG_OFF);
    u16* H   = (u16*)(ws + H_OFF);
    int*   eidx = (int*)(ws + SM_OFF);                 // 32 KB
    float* gp   = (float*)(ws + SM_OFF + 32768);       // 32 KB
    int*   slot = (int*)(ws + SM_OFF + 65536);         // 32 KB
    int*   tos  = (int*)(ws + SM_OFF + 98304);         // 32 KB
    float* me   = (float*)(ws + SM_OFF + 131072);      // 64 B
    float* wgT  = (float*)(ws + SM_OFF + 131072 + 128);// 64 KB (16B aligned)

    float* tail = out + (size_t)TOK * DIM;             // [l_aux, exp_counts x16]

    moe_init<<<1, 64, 0, stream>>>(me);
    moe_wgT<<<64, 256, 0, stream>>>(wg, wgT);
    moe_gate<<<TOK / 16, 256, 0, stream>>>(x, wgT, eidx, gp, me);
    moe_scan<<<1, 1024, 0, stream>>>(eidx, me, slot, tos, tail);
    moe_gather<<<NE * CAP, 256, 0, stream>>>(x, tos, Xg);
    moe_zero_dropped<<<TOK, 256, 0, stream>>>(slot, out);
    moe_convT<<<NE * (DIM / 64) * (NF / 64), 256, 0, stream>>>(w1, Wbf, DIM, NF);
    moe_gemm1<<<512, 512, 0, stream>>>(Xg, Wbf, b1, H);
    moe_convT<<<NE * (NF / 64) * (DIM / 64), 256, 0, stream>>>(w2, Wbf, NF, DIM);
    moe_gemm2<<<256, 512, 0, stream>>>(H, Wbf, b2, tos, gp, out);
}

// Round 4
// 917.537 us; speedup vs baseline: 1.0276x; 1.0129x over previous
//
#include <hip/hip_runtime.h>

typedef unsigned short u16;
typedef unsigned int   u32;
typedef unsigned long long u64;
typedef __attribute__((ext_vector_type(8))) __bf16 bf16x8;
typedef __attribute__((ext_vector_type(4))) float  f32x4;

#define TOK 8192
#define DIM 1024
#define NE  16
#define NF  4096
#define CAP 512

// ---------- helpers ----------
__device__ __forceinline__ u16 f2bf(float f) {
    u32 u = __float_as_uint(f);
    u32 r = (u + 0x7FFFu + ((u >> 16) & 1u)) >> 16;   // RNE
    return (u16)r;
}

__device__ __forceinline__ float gelu_tanh(float x) {
    float u = 0.7978845608028654f * (x + 0.044715f * x * x * x);
    float t = __expf(-2.f * fabsf(u));
    float th = (1.f - t) / (1.f + t);
    th = (u < 0.f) ? -th : th;
    return 0.5f * x * (1.f + th);
}

__device__ __forceinline__ void gld16(const void* g, void* l) {
    __builtin_amdgcn_global_load_lds(
        (const __attribute__((address_space(1))) void*)g,
        (__attribute__((address_space(3))) void*)l, 16, 0, 0);
}

// ---------- small kernels ----------
__global__ void moe_init(float* me_sums) {
    if (threadIdx.x < NE) me_sums[threadIdx.x] = 0.f;
}

__global__ void moe_wgT(const float* __restrict__ wg, float* __restrict__ wgT) {
    int i = blockIdx.x * 256 + threadIdx.x;     // 16384 elements
    int d = i >> 4, e = i & 15;
    wgT[(size_t)e * DIM + d] = wg[i];
}

// one thread per (token, expert); 256 thr = 16 tokens x 16 experts
__global__ void moe_gate(const float* __restrict__ x, const float* __restrict__ wgT,
                         int* __restrict__ eidx, float* __restrict__ gp,
                         float* __restrict__ me_sums) {
    __shared__ float lme[NE];
    const int tid = threadIdx.x;
    if (tid < NE) lme[tid] = 0.f;
    __syncthreads();
    const int tok = blockIdx.x * 16 + (tid >> 4);
    const int e   = tid & 15;
    const float4* xp = (const float4*)(x + (size_t)tok * DIM);
    const float4* wp = (const float4*)(wgT + (size_t)e * DIM);
    float acc = 0.f;
#pragma unroll 4
    for (int i = 0; i < DIM / 4; ++i) {
        float4 a = xp[i], b = wp[i];
        acc = fmaf(a.x, b.x, acc); acc = fmaf(a.y, b.y, acc);
        acc = fmaf(a.z, b.z, acc); acc = fmaf(a.w, b.w, acc);
    }
    // softmax across the 16-lane expert group
    float mx = acc;
    for (int off = 8; off; off >>= 1) mx = fmaxf(mx, __shfl_xor(mx, off, 16));
    float ex = __expf(acc - mx);
    float sum = ex;
    for (int off = 8; off; off >>= 1) sum += __shfl_xor(sum, off, 16);
    float p = ex / sum;
    atomicAdd(&lme[e], p);
    // argmax (first index on ties, matching jnp.argmax)
    float bv = acc; int bi = e;
    for (int off = 8; off; off >>= 1) {
        float ov = __shfl_xor(bv, off, 16);
        int   oi = __shfl_xor(bi, off, 16);
        if (ov > bv || (ov == bv && oi < bi)) { bv = ov; bi = oi; }
    }
    float pw = __shfl(p, bi, 16);
    if (e == 0) { eidx[tok] = bi; gp[tok] = pw; }
    __syncthreads();
    if (tid < 16) atomicAdd(&me_sums[tid], lme[tid]);
}

// single block, 1024 threads: ordered cumsum slot assignment + counts + l_aux
__global__ void moe_scan(const int* __restrict__ eidx, const float* __restrict__ me_sums,
                         int* __restrict__ slot, int* __restrict__ tos,
                         float* __restrict__ tail /* d_out + TOK*DIM */) {
    __shared__ int wcnt[16][16];
    __shared__ int base[16];
    const int tid = threadIdx.x, wid = tid >> 6, lane = tid & 63;
    if (tid < 16) base[tid] = 0;
    for (int i = tid; i < NE * CAP; i += 1024) tos[i] = -1;
    __syncthreads();
    const u64 below = ((u64)1 << lane) - 1;
    for (int chunk = 0; chunk < TOK / 1024; ++chunk) {
        int t = chunk * 1024 + tid;
        int e = eidx[t];
        int rank = 0;
#pragma unroll
        for (int ex = 0; ex < 16; ++ex) {
            u64 m = __ballot(e == ex);
            if (e == ex)    rank = __popcll(m & below);
            if (lane == ex) wcnt[wid][ex] = __popcll(m);
        }
        __syncthreads();
        int pre = base[e];
        for (int w = 0; w < wid; ++w) pre += wcnt[w][e];
        int s = pre + rank;
        slot[t] = s;
        if (s < CAP) tos[e * CAP + s] = t;
        __syncthreads();
        if (tid < 16) {
            int tot = 0;
            for (int w = 0; w < 16; ++w) tot += wcnt[w][tid];
            base[tid] += tot;
        }
        __syncthreads();
    }
    if (tid == 0) {
        float laux = 0.f;
        for (int e2 = 0; e2 < 16; ++e2) {
            float me = me_sums[e2] / (float)TOK;
            float ce = (float)base[e2] / (float)TOK;
            laux += me * ce;
        }
        tail[0] = laux * (float)NE;
    }
    if (tid < 16) tail[1 + tid] = (float)base[tid];
}

// one block per slot row: gather x[token] -> bf16 Xg[slot]
__global__ void moe_gather(const float* __restrict__ x, const int* __restrict__ tos,
                           u16* __restrict__ Xg) {
    const int s = blockIdx.x, tid = threadIdx.x;
    const int t = tos[s];
    float4 v = make_float4(0.f, 0.f, 0.f, 0.f);
    if (t >= 0) v = *(const float4*)(x + (size_t)t * DIM + tid * 4);
    u32 lo = (u32)f2bf(v.x) | ((u32)f2bf(v.y) << 16);
    u32 hi = (u32)f2bf(v.z) | ((u32)f2bf(v.w) << 16);
    *(uint2*)(Xg + (size_t)s * DIM + tid * 4) = make_uint2(lo, hi);
}

__global__ void moe_zero_dropped(const int* __restrict__ slot, float* __restrict__ out) {
    const int t = blockIdx.x;
    if (slot[t] < CAP) return;
    *(float4*)(out + (size_t)t * DIM + threadIdx.x * 4) = make_float4(0.f, 0.f, 0.f, 0.f);
}

// transpose+convert: src [E][R][C] f32 -> dst [E][C][R] bf16 (64x64 tiles)
__global__ void moe_convT(const float* __restrict__ src, u16* __restrict__ dst,
                          int R, int C) {
    __shared__ float tile[64][65];
    int b = blockIdx.x;
    const int tilesC = C >> 6, tilesR = R >> 6;
    int tc = b % tilesC; b /= tilesC;
    int tr = b % tilesR; int e = b / tilesR;
    const float* S = src + ((size_t)e * R + tr * 64) * C + tc * 64;
    const int tid = threadIdx.x;
    const int rr = tid >> 4, cc = (tid & 15) * 4;
#pragma unroll
    for (int i = 0; i < 4; ++i) {
        float4 v = *(const float4*)(S + (size_t)(rr + i * 16) * C + cc);
        tile[rr + i * 16][cc + 0] = v.x; tile[rr + i * 16][cc + 1] = v.y;
        tile[rr + i * 16][cc + 2] = v.z; tile[rr + i * 16][cc + 3] = v.w;
    }
    __syncthreads();
    const int c = tid >> 2, r0 = (tid & 3) * 16;
    u16 tmp[16];
#pragma unroll
    for (int k = 0; k < 16; ++k) tmp[k] = f2bf(tile[r0 + k][c]);
    u16* D = dst + ((size_t)e * C + tc * 64 + c) * R + tr * 64 + r0;
    uint4 w0 = make_uint4((u32)tmp[0] | ((u32)tmp[1] << 16), (u32)tmp[2] | ((u32)tmp[3] << 16),
                          (u32)tmp[4] | ((u32)tmp[5] << 16), (u32)tmp[6] | ((u32)tmp[7] << 16));
    uint4 w1 = make_uint4((u32)tmp[8] | ((u32)tmp[9] << 16), (u32)tmp[10] | ((u32)tmp[11] << 16),
                          (u32)tmp[12] | ((u32)tmp[13] << 16), (u32)tmp[14] | ((u32)tmp[15] << 16));
    *(uint4*)(D) = w0;
    *(uint4*)(D + 8) = w1;
}

// ---------- GEMM1: H = gelu(Xg @ w1 + b1), bf16 out ----------
// 256x256 tile, BK=32, 8 waves (2Mx4N). Fine-phase schedule (T3+T4+T5):
// per K-tile two phases, each {ds_read frags || issue half next-stage ->
// s_barrier -> lgkmcnt(0) -> setprio(1) 16xMFMA setprio(0) -> s_barrier}.
// 4 LDS buffers (128 KB), 3 tiles in flight, counted vmcnt (8/4/0 tail).
__global__ __launch_bounds__(512, 2) void moe_gemm1(const u16* __restrict__ Xg,
                                                    const u16* __restrict__ W1t,
                                                    const float* __restrict__ b1,
                                                    u16* __restrict__ H) {
    __shared__ alignas(16) u16 Als[4][8192];   // 4 x (256 rows x 32k) = 64 KB
    __shared__ alignas(16) u16 Bls[4][8192];   // 4 x (256 rows x 32k) = 64 KB
    const int tid = threadIdx.x, wave = tid >> 6, lane = tid & 63;
    const int flat = blockIdx.x;            // 0..511
    const int xcd  = flat & 7;
    const int slot = flat >> 3;             // 0..63
    const int e    = xcd * 2 + (slot >> 5); // 2 experts per XCD
    const int tile = slot & 31;             // 0..31
    const int bm   = tile & 1;              // 2 m-tiles (bm fastest)
    const int bn   = tile >> 1;             // 0..15
    const int r4   = lane >> 2;
    const int gch  = (lane & 3) ^ ((lane >> 3) & 3);   // source chunk pre-swizzle
    const u16* aSrc = Xg + (size_t)(e * 512 + bm * 256 + wave * 16 + r4) * DIM + gch * 8;
    const u16* bSrc = W1t + (size_t)e * NF * DIM
                    + (size_t)(bn * 256 + wave * 16 + r4) * DIM + gch * 8;
    const int wm = wave & 1, wn = wave >> 1;           // 2M x 4N wave grid
    const int fr = lane & 15, fq = lane >> 4;
    const int rdoff = fr * 32 + (fq ^ ((fr >> 1) & 3)) * 8;  // swizzled read offset

    f32x4 acc[2][4][4] = {};

#define STG1A(P, T) do { const int ko = (T) * 32; u16* ad = &Als[P][wave * 512]; \
        gld16(aSrc + ko, ad); gld16(aSrc + 128 * DIM + ko, ad + 4096); } while (0)
#define STG1B(P, T) do { const int ko = (T) * 32; u16* bd = &Bls[P][wave * 512]; \
        gld16(bSrc + ko, bd); gld16(bSrc + 128 * DIM + ko, bd + 4096); } while (0)

    const int NT = DIM / 32;               // 32 K-tiles
    STG1A(0, 0); STG1B(0, 0);
    STG1A(1, 1); STG1B(1, 1);
    STG1A(2, 2); STG1B(2, 2);
    for (int t = 0; t < NT; ++t) {
        const int c = t & 3;
        const int rem = NT - 1 - t;
        // tile t's 4 loads are the oldest outstanding (FIFO); drain exactly them
        if (rem >= 2)      asm volatile("s_waitcnt vmcnt(8)" ::: "memory");
        else if (rem == 1) asm volatile("s_waitcnt vmcnt(4)" ::: "memory");
        else               asm volatile("s_waitcnt vmcnt(0)" ::: "memory");
        __builtin_amdgcn_sched_barrier(0);
        __builtin_amdgcn_s_barrier();      // tile t visible to all; buf (c+3)&3 free
        __builtin_amdgcn_sched_barrier(0);
        const u16* Ab = &Als[c][0];
        const u16* Bb = &Bls[c][0];
        bf16x8 bF[4], aF[4];
        // ---- phase A: B frags + A quad0 reads, stage A-half of t+3 ----
#pragma unroll
        for (int j = 0; j < 4; ++j)
            bF[j] = *(const bf16x8*)(const void*)(Bb + (wn * 64 + j * 16) * 32 + rdoff);
#pragma unroll
        for (int i = 0; i < 4; ++i)
            aF[i] = *(const bf16x8*)(const void*)(Ab + (wm * 128 + i * 16) * 32 + rdoff);
        if (t + 3 < NT) STG1A((c + 3) & 3, t + 3);
        __builtin_amdgcn_sched_barrier(0);
        asm volatile("s_waitcnt lgkmcnt(0)" ::: "memory");
        __builtin_amdgcn_sched_barrier(0);
        __builtin_amdgcn_s_setprio(1);
#pragma unroll
        for (int i = 0; i < 4; ++i)
#pragma unroll
            for (int j = 0; j < 4; ++j)
                acc[0][i][j] = __builtin_amdgcn_mfma_f32_16x16x32_bf16(aF[i], bF[j], acc[0][i][j], 0, 0, 0);
        __builtin_amdgcn_s_setprio(0);
        __builtin_amdgcn_sched_barrier(0);
        __builtin_amdgcn_s_barrier();      // phase boundary
        __builtin_amdgcn_sched_barrier(0);
        // ---- phase B: A quad1 reads, stage B-half of t+3 ----
#pragma unroll
        for (int i = 0; i < 4; ++i)
            aF[i] = *(const bf16x8*)(const void*)(Ab + (wm * 128 + 64 + i * 16) * 32 + rdoff);
        if (t + 3 < NT) STG1B((c + 3) & 3, t + 3);
        __builtin_amdgcn_sched_barrier(0);
        asm volatile("s_waitcnt lgkmcnt(0)" ::: "memory");
        __builtin_amdgcn_sched_barrier(0);
        __builtin_amdgcn_s_setprio(1);
#pragma unroll
        for (int i = 0; i < 4; ++i)
#pragma unroll
            for (int j = 0; j < 4; ++j)
                acc[1][i][j] = __builtin_amdgcn_mfma_f32_16x16x32_bf16(aF[i], bF[j], acc[1][i][j], 0, 0, 0);
        __builtin_amdgcn_s_setprio(0);
    }
#undef STG1A
#undef STG1B

    const int mBase = e * 512 + bm * 256 + wm * 128;
    const int nBase = bn * 256 + wn * 64;
#pragma unroll
    for (int j = 0; j < 4; ++j) {
        const int f = nBase + j * 16 + fr;
        const float bias = b1[e * NF + f];
#pragma unroll
        for (int q = 0; q < 2; ++q)
#pragma unroll
            for (int i = 0; i < 4; ++i) {
                const int m0 = mBase + q * 64 + i * 16 + fq * 4;
#pragma unroll
                for (int r = 0; r < 4; ++r) {
                    float v = acc[q][i][j][r] + bias;
                    H[(size_t)(m0 + r) * NF + f] = f2bf(gelu_tanh(v));
                }
            }
    }
}

// ---------- GEMM2: out[token] = gate * (H @ w2 + b2), scattered ----------
// 256x128 tile, BK=32, same fine-phase schedule. 3 loads/tile (A2+B1),
// 4 LDS buffers (96 KB), counted vmcnt (6/3/0 tail).
__global__ __launch_bounds__(512, 2) void moe_gemm2(const u16* __restrict__ H,
                                                    const u16* __restrict__ W2t,
                                                    const float* __restrict__ b2,
                                                    const int* __restrict__ tos,
                                                    const float* __restrict__ gp,
                                                    float* __restrict__ out) {
    __shared__ alignas(16) u16 Als[4][8192];   // 4 x (256 x 32) = 64 KB
    __shared__ alignas(16) u16 Bls[4][4096];   // 4 x (128 x 32) = 32 KB
    const int tid = threadIdx.x, wave = tid >> 6, lane = tid & 63;
    const int flat = blockIdx.x;            // 0..255
    const int xcd  = flat & 7;
    const int slot = flat >> 3;             // 0..31
    const int e    = xcd * 2 + (slot >> 4); // 2 experts per XCD
    const int tile = slot & 15;             // 0..15
    const int bm   = tile & 1;
    const int bn   = tile >> 1;             // 0..7
    const int r4   = lane >> 2;
    const int gch  = (lane & 3) ^ ((lane >> 3) & 3);
    const u16* aSrc = H + (size_t)(e * 512 + bm * 256 + wave * 16 + r4) * NF + gch * 8;
    const u16* bSrc = W2t + (size_t)e * DIM * NF
                    + (size_t)(bn * 128 + wave * 16 + r4) * NF + gch * 8;
    const int wm = wave & 1, wn = wave >> 1;
    const int fr = lane & 15, fq = lane >> 4;
    const int rdoff = fr * 32 + (fq ^ ((fr >> 1) & 3)) * 8;

    f32x4 acc[2][4][2] = {};

#define STG2A(P, T) do { const int ko = (T) * 32; u16* ad = &Als[P][wave * 512]; \
        gld16(aSrc + ko, ad); gld16(aSrc + (size_t)128 * NF + ko, ad + 4096); } while (0)
#define STG2B(P, T) do { const int ko = (T) * 32; u16* bd = &Bls[P][wave * 512]; \
        gld16(bSrc + ko, bd); } while (0)

    const int NT = NF / 32;                // 128 K-tiles
    STG2A(0, 0); STG2B(0, 0);
    STG2A(1, 1); STG2B(1, 1);
    STG2A(2, 2); STG2B(2, 2);
    for (int t = 0; t < NT; ++t) {
        const int c = t & 3;
        const int rem = NT - 1 - t;
        if (rem >= 2)      asm volatile("s_waitcnt vmcnt(6)" ::: "memory");
        else if (rem == 1) asm volatile("s_waitcnt vmcnt(3)" ::: "memory");
        else               asm volatile("s_waitcnt vmcnt(0)" ::: "memory");
        __builtin_amdgcn_sched_barrier(0);
        __builtin_amdgcn_s_barrier();
        __builtin_amdgcn_sched_barrier(0);
        const u16* Ab = &Als[c][0];
        const u16* Bb = &Bls[c][0];
        bf16x8 bF[2], aF[4];
        // ---- phase A ----
#pragma unroll
        for (int j = 0; j < 2; ++j)
            bF[j] = *(const bf16x8*)(const void*)(Bb + (wn * 32 + j * 16) * 32 + rdoff);
#pragma unroll
        for (int i = 0; i < 4; ++i)
            aF[i] = *(const bf16x8*)(const void*)(Ab + (wm * 128 + i * 16) * 32 + rdoff);
        if (t + 3 < NT) STG2A((c + 3) & 3, t + 3);
        __builtin_amdgcn_sched_barrier(0);
        asm volatile("s_waitcnt lgkmcnt(0)" ::: "memory");
        __builtin_amdgcn_sched_barrier(0);
        __builtin_amdgcn_s_setprio(1);
#pragma unroll
        for (int i = 0; i < 4; ++i)
#pragma unroll
            for (int j = 0; j < 2; ++j)
                acc[0][i][j] = __builtin_amdgcn_mfma_f32_16x16x32_bf16(aF[i], bF[j], acc[0][i][j], 0, 0, 0);
        __builtin_amdgcn_s_setprio(0);
        __builtin_amdgcn_sched_barrier(0);
        __builtin_amdgcn_s_barrier();
        __builtin_amdgcn_sched_barrier(0);
        // ---- phase B ----
#pragma unroll
        for (int i = 0; i < 4; ++i)
            aF[i] = *(const bf16x8*)(const void*)(Ab + (wm * 128 + 64 + i * 16) * 32 + rdoff);
        if (t + 3 < NT) STG2B((c + 3) & 3, t + 3);
        __builtin_amdgcn_sched_barrier(0);
        asm volatile("s_waitcnt lgkmcnt(0)" ::: "memory");
        __builtin_amdgcn_sched_barrier(0);
        __builtin_amdgcn_s_setprio(1);
#pragma unroll
        for (int i = 0; i < 4; ++i)
#pragma unroll
            for (int j = 0; j < 2; ++j)
                acc[1][i][j] = __builtin_amdgcn_mfma_f32_16x16x32_bf16(aF[i], bF[j], acc[1][i][j], 0, 0, 0);
        __builtin_amdgcn_s_setprio(0);
    }
#undef STG2A
#undef STG2B

    const int mBase = e * 512 + bm * 256 + wm * 128;
    const int nBase = bn * 128 + wn * 32;
#pragma unroll
    for (int q = 0; q < 2; ++q)
#pragma unroll
        for (int i = 0; i < 4; ++i) {
#pragma unroll
            for (int r = 0; r < 4; ++r) {
                const int m = mBase + q * 64 + i * 16 + fq * 4 + r;
                const int t = tos[m];
                if (t < 0) continue;
                const float g = gp[t];
#pragma unroll
                for (int j = 0; j < 2; ++j) {
                    const int d = nBase + j * 16 + fr;
                    out[(size_t)t * DIM + d] = g * (acc[q][i][j][r] + b2[e * DIM + d]);
                }
            }
        }
}

// ---------- launch ----------
extern "C" void kernel_launch(void* const* d_in, const int* in_sizes, int n_in,
                              void* d_out, int out_size, void* d_ws, size_t ws_size,
                              hipStream_t stream) {
    const float* x  = (const float*)d_in[0];
    const float* wg = (const float*)d_in[1];
    const float* w1 = (const float*)d_in[2];
    const float* b1 = (const float*)d_in[3];
    const float* w2 = (const float*)d_in[4];
    const float* b2 = (const float*)d_in[5];
    float* out = (float*)d_out;

    char* ws = (char*)d_ws;
    const size_t WBF_OFF = 0;                                   // 134,217,728 B (shared by w1/w2 bf16)
    const size_t XG_OFF  = WBF_OFF + (size_t)NE * NF * DIM * 2; // 16,777,216 B
    const size_t H_OFF   = XG_OFF + (size_t)TOK * DIM * 2;      // 67,108,864 B
    const size_t SM_OFF  = H_OFF + (size_t)TOK * NF * 2;
    u16* Wbf = (u16*)(ws + WBF_OFF);
    u16* Xg  = (u16*)(ws + XG_OFF);
    u16* H   = (u16*)(ws + H_OFF);
    int*   eidx = (int*)(ws + SM_OFF);                 // 32 KB
    float* gp   = (float*)(ws + SM_OFF + 32768);       // 32 KB
    int*   slot = (int*)(ws + SM_OFF + 65536);         // 32 KB
    int*   tos  = (int*)(ws + SM_OFF + 98304);         // 32 KB
    float* me   = (float*)(ws + SM_OFF + 131072);      // 64 B
    float* wgT  = (float*)(ws + SM_OFF + 131072 + 128);// 64 KB (16B aligned)

    float* tail = out + (size_t)TOK * DIM;             // [l_aux, exp_counts x16]

    moe_init<<<1, 64, 0, stream>>>(me);
    moe_wgT<<<64, 256, 0, stream>>>(wg, wgT);
    moe_gate<<<TOK / 16, 256, 0, stream>>>(x, wgT, eidx, gp, me);
    moe_scan<<<1, 1024, 0, stream>>>(eidx, me, slot, tos, tail);
    moe_gather<<<NE * CAP, 256, 0, stream>>>(x, tos, Xg);
    moe_zero_dropped<<<TOK, 256, 0, stream>>>(slot, out);
    moe_convT<<<NE * (DIM / 64) * (NF / 64), 256, 0, stream>>>(w1, Wbf, DIM, NF);
    moe_gemm1<<<512, 512, 0, stream>>>(Xg, Wbf, b1, H);
    moe_convT<<<NE * (NF / 64) * (DIM / 64), 256, 0, stream>>>(w2, Wbf, NF, DIM);
    moe_gemm2<<<256, 512, 0, stream>>>(H, Wbf, b2, tos, gp, out);
}

// Round 5
// 889.742 us; speedup vs baseline: 1.0597x; 1.0312x over previous
//
#include <hip/hip_runtime.h>

typedef unsigned short u16;
typedef unsigned int   u32;
typedef unsigned long long u64;
typedef __attribute__((ext_vector_type(8))) __bf16 bf16x8;
typedef __attribute__((ext_vector_type(4))) float  f32x4;

#define TOK 8192
#define DIM 1024
#define NE  16
#define NF  4096
#define CAP 512

// ---------- helpers ----------
__device__ __forceinline__ u16 f2bf(float f) {
    u32 u = __float_as_uint(f);
    u32 r = (u + 0x7FFFu + ((u >> 16) & 1u)) >> 16;   // RNE
    return (u16)r;
}

__device__ __forceinline__ float gelu_tanh(float x) {
    float u = 0.7978845608028654f * (x + 0.044715f * x * x * x);
    float t = __expf(-2.f * fabsf(u));
    float th = (1.f - t) / (1.f + t);
    th = (u < 0.f) ? -th : th;
    return 0.5f * x * (1.f + th);
}

__device__ __forceinline__ void gld16(const void* g, void* l) {
    __builtin_amdgcn_global_load_lds(
        (const __attribute__((address_space(1))) void*)g,
        (__attribute__((address_space(3))) void*)l, 16, 0, 0);
}

// ---------- small kernels ----------
__global__ void moe_wgT(const float* __restrict__ wg, float* __restrict__ wgT,
                        float* __restrict__ me_sums) {
    int i = blockIdx.x * 256 + threadIdx.x;     // 16384 elements
    if (i < NE) me_sums[i] = 0.f;
    int d = i >> 4, e = i & 15;
    wgT[(size_t)e * DIM + d] = wg[i];
}

// one thread per (token, expert); 256 thr = 16 tokens x 16 experts
__global__ void moe_gate(const float* __restrict__ x, const float* __restrict__ wgT,
                         int* __restrict__ eidx, float* __restrict__ gp,
                         float* __restrict__ me_sums) {
    __shared__ float lme[NE];
    const int tid = threadIdx.x;
    if (tid < NE) lme[tid] = 0.f;
    __syncthreads();
    const int tok = blockIdx.x * 16 + (tid >> 4);
    const int e   = tid & 15;
    const float4* xp = (const float4*)(x + (size_t)tok * DIM);
    const float4* wp = (const float4*)(wgT + (size_t)e * DIM);
    float acc = 0.f;
#pragma unroll 4
    for (int i = 0; i < DIM / 4; ++i) {
        float4 a = xp[i], b = wp[i];
        acc = fmaf(a.x, b.x, acc); acc = fmaf(a.y, b.y, acc);
        acc = fmaf(a.z, b.z, acc); acc = fmaf(a.w, b.w, acc);
    }
    // softmax across the 16-lane expert group
    float mx = acc;
    for (int off = 8; off; off >>= 1) mx = fmaxf(mx, __shfl_xor(mx, off, 16));
    float ex = __expf(acc - mx);
    float sum = ex;
    for (int off = 8; off; off >>= 1) sum += __shfl_xor(sum, off, 16);
    float p = ex / sum;
    atomicAdd(&lme[e], p);
    // argmax (first index on ties, matching jnp.argmax)
    float bv = acc; int bi = e;
    for (int off = 8; off; off >>= 1) {
        float ov = __shfl_xor(bv, off, 16);
        int   oi = __shfl_xor(bi, off, 16);
        if (ov > bv || (ov == bv && oi < bi)) { bv = ov; bi = oi; }
    }
    float pw = __shfl(p, bi, 16);
    if (e == 0) { eidx[tok] = bi; gp[tok] = pw; }
    __syncthreads();
    if (tid < 16) atomicAdd(&me_sums[tid], lme[tid]);
}

// single block, 1024 threads: ordered cumsum slot assignment + counts + l_aux
__global__ void moe_scan(const int* __restrict__ eidx, const float* __restrict__ me_sums,
                         int* __restrict__ slot, int* __restrict__ tos,
                         float* __restrict__ tail /* d_out + TOK*DIM */) {
    __shared__ int wcnt[16][16];
    __shared__ int base[16];
    const int tid = threadIdx.x, wid = tid >> 6, lane = tid & 63;
    if (tid < 16) base[tid] = 0;
    for (int i = tid; i < NE * CAP; i += 1024) tos[i] = -1;
    __syncthreads();
    const u64 below = ((u64)1 << lane) - 1;
    for (int chunk = 0; chunk < TOK / 1024; ++chunk) {
        int t = chunk * 1024 + tid;
        int e = eidx[t];
        int rank = 0;
#pragma unroll
        for (int ex = 0; ex < 16; ++ex) {
            u64 m = __ballot(e == ex);
            if (e == ex)    rank = __popcll(m & below);
            if (lane == ex) wcnt[wid][ex] = __popcll(m);
        }
        __syncthreads();
        int pre = base[e];
        for (int w = 0; w < wid; ++w) pre += wcnt[w][e];
        int s = pre + rank;
        slot[t] = s;
        if (s < CAP) tos[e * CAP + s] = t;
        __syncthreads();
        if (tid < 16) {
            int tot = 0;
            for (int w = 0; w < 16; ++w) tot += wcnt[w][tid];
            base[tid] += tot;
        }
        __syncthreads();
    }
    if (tid == 0) {
        float laux = 0.f;
        for (int e2 = 0; e2 < 16; ++e2) {
            float me = me_sums[e2] / (float)TOK;
            float ce = (float)base[e2] / (float)TOK;
            laux += me * ce;
        }
        tail[0] = laux * (float)NE;
    }
    if (tid < 16) tail[1 + tid] = (float)base[tid];
}

// one block per slot row: gather x[token] -> bf16 Xg[slot]; also zero dropped tokens
__global__ void moe_gather_zero(const float* __restrict__ x, const int* __restrict__ tos,
                                const int* __restrict__ slot, u16* __restrict__ Xg,
                                float* __restrict__ out) {
    const int b = blockIdx.x, tid = threadIdx.x;
    const int t = tos[b];
    float4 v = make_float4(0.f, 0.f, 0.f, 0.f);
    if (t >= 0) v = *(const float4*)(x + (size_t)t * DIM + tid * 4);
    u32 lo = (u32)f2bf(v.x) | ((u32)f2bf(v.y) << 16);
    u32 hi = (u32)f2bf(v.z) | ((u32)f2bf(v.w) << 16);
    *(uint2*)(Xg + (size_t)b * DIM + tid * 4) = make_uint2(lo, hi);
    // b doubles as a token index for the dropped-token zeroing
    if (slot[b] >= CAP)
        *(float4*)(out + (size_t)b * DIM + tid * 4) = make_float4(0.f, 0.f, 0.f, 0.f);
}

// transpose+convert: src [E][R][C] f32 -> dst [E][C][R] bf16 (64x64 tiles)
__global__ void moe_convT(const float* __restrict__ src, u16* __restrict__ dst,
                          int R, int C) {
    __shared__ float tile[64][65];
    int b = blockIdx.x;
    const int tilesC = C >> 6, tilesR = R >> 6;
    int tc = b % tilesC; b /= tilesC;
    int tr = b % tilesR; int e = b / tilesR;
    const float* S = src + ((size_t)e * R + tr * 64) * C + tc * 64;
    const int tid = threadIdx.x;
    const int rr = tid >> 4, cc = (tid & 15) * 4;
#pragma unroll
    for (int i = 0; i < 4; ++i) {
        float4 v = *(const float4*)(S + (size_t)(rr + i * 16) * C + cc);
        tile[rr + i * 16][cc + 0] = v.x; tile[rr + i * 16][cc + 1] = v.y;
        tile[rr + i * 16][cc + 2] = v.z; tile[rr + i * 16][cc + 3] = v.w;
    }
    __syncthreads();
    const int c = tid >> 2, r0 = (tid & 3) * 16;
    u16 tmp[16];
#pragma unroll
    for (int k = 0; k < 16; ++k) tmp[k] = f2bf(tile[r0 + k][c]);
    u16* D = dst + ((size_t)e * C + tc * 64 + c) * R + tr * 64 + r0;
    uint4 w0 = make_uint4((u32)tmp[0] | ((u32)tmp[1] << 16), (u32)tmp[2] | ((u32)tmp[3] << 16),
                          (u32)tmp[4] | ((u32)tmp[5] << 16), (u32)tmp[6] | ((u32)tmp[7] << 16));
    uint4 w1 = make_uint4((u32)tmp[8] | ((u32)tmp[9] << 16), (u32)tmp[10] | ((u32)tmp[11] << 16),
                          (u32)tmp[12] | ((u32)tmp[13] << 16), (u32)tmp[14] | ((u32)tmp[15] << 16));
    *(uint4*)(D) = w0;
    *(uint4*)(D + 8) = w1;
}

// ---------- fat kernel: GEMM1 (256x128, 48 KB LDS, 2 blk/CU) + convT(w2) ----------
// grid 5120 x 512thr: bid%5==0 -> gemm block (1024 total), else conv block (4096,
// each doing 4 of the old 64x64 conv tiles). Conv BW streams while gemm MFMAs run
// on the co-resident block; standalone convT2 dispatch eliminated.
// gemm: minimal 2-phase counted pipeline (T3 recipe): stage(t+1) -> ds_read ->
// MFMA -> vmcnt(0)+barrier. XCD ownership via physical bid (5g mod 8 bijective).
__global__ __launch_bounds__(512, 4) void moe_gemm1cv(const u16* __restrict__ Xg,
                                                      const u16* __restrict__ W1t,
                                                      const float* __restrict__ b1,
                                                      u16* __restrict__ H,
                                                      const float* __restrict__ w2,
                                                      u16* __restrict__ W2t) {
    __shared__ alignas(16) char smem[49152];
    const int bid = blockIdx.x;
    const int tid = threadIdx.x;
    if (bid % 5 == 0) {
        // ---------------- GEMM mode ----------------
        u16* Als = (u16*)smem;              // 2 x (256x32) = 32 KB
        u16* Bls = (u16*)(smem + 32768);    // 2 x (128x32) = 16 KB
        const int g    = bid / 5;           // 0..1023
        const int wave = tid >> 6, lane = tid & 63;
        const int xcd  = bid & 7;           // physical XCD
        const int h    = g >> 3;            // 0..127 within XCD
        const int e    = xcd * 2 + (h >> 6);
        const int tl   = h & 63;
        const int bm   = tl & 1;
        const int bn   = tl >> 1;           // 0..31
        const int r4   = lane >> 2;
        const int gch  = (lane & 3) ^ ((lane >> 3) & 3);
        const u16* aSrc = Xg + (size_t)(e * 512 + bm * 256 + wave * 16 + r4) * DIM + gch * 8;
        const u16* bSrc = W1t + (size_t)e * NF * DIM
                        + (size_t)(bn * 128 + wave * 16 + r4) * DIM + gch * 8;
        const int wm = wave & 1, wn = wave >> 1;
        const int fr = lane & 15, fq = lane >> 4;
        const int rdoff = fr * 32 + (fq ^ ((fr >> 1) & 3)) * 8;
        f32x4 acc[2][4][2] = {};

#define STG1(P, T) do { const int ko = (T) * 32; \
        u16* ad = Als + (P) * 8192 + wave * 512; \
        u16* bd = Bls + (P) * 4096 + wave * 512; \
        gld16(aSrc + ko, ad); gld16(aSrc + 128 * DIM + ko, ad + 4096); \
        gld16(bSrc + ko, bd); } while (0)

        const int NT = DIM / 32;            // 32 K-tiles
        STG1(0, 0);
        asm volatile("s_waitcnt vmcnt(0)" ::: "memory");
        __builtin_amdgcn_s_barrier();
        int cur = 0;
        for (int t = 0; t < NT; ++t) {
            if (t + 1 < NT) STG1(cur ^ 1, t + 1);
            const u16* Ab = Als + cur * 8192;
            const u16* Bb = Bls + cur * 4096;
            bf16x8 aF[4], bF[2];
#pragma unroll
            for (int j = 0; j < 2; ++j)
                bF[j] = *(const bf16x8*)(const void*)(Bb + (wn * 32 + j * 16) * 32 + rdoff);
#pragma unroll
            for (int i = 0; i < 4; ++i)
                aF[i] = *(const bf16x8*)(const void*)(Ab + (wm * 128 + i * 16) * 32 + rdoff);
            __builtin_amdgcn_s_setprio(1);
#pragma unroll
            for (int i = 0; i < 4; ++i)
#pragma unroll
                for (int j = 0; j < 2; ++j)
                    acc[0][i][j] = __builtin_amdgcn_mfma_f32_16x16x32_bf16(aF[i], bF[j], acc[0][i][j], 0, 0, 0);
            __builtin_amdgcn_s_setprio(0);
#pragma unroll
            for (int i = 0; i < 4; ++i)
                aF[i] = *(const bf16x8*)(const void*)(Ab + (wm * 128 + 64 + i * 16) * 32 + rdoff);
            __builtin_amdgcn_s_setprio(1);
#pragma unroll
            for (int i = 0; i < 4; ++i)
#pragma unroll
                for (int j = 0; j < 2; ++j)
                    acc[1][i][j] = __builtin_amdgcn_mfma_f32_16x16x32_bf16(aF[i], bF[j], acc[1][i][j], 0, 0, 0);
            __builtin_amdgcn_s_setprio(0);
            asm volatile("s_waitcnt vmcnt(0)" ::: "memory");
            __builtin_amdgcn_s_barrier();
            cur ^= 1;
        }
#undef STG1
        const int mBase = e * 512 + bm * 256 + wm * 128;
        const int nBase = bn * 128 + wn * 32;
#pragma unroll
        for (int j = 0; j < 2; ++j) {
            const int f = nBase + j * 16 + fr;
            const float bias = b1[e * NF + f];
#pragma unroll
            for (int q = 0; q < 2; ++q)
#pragma unroll
                for (int i = 0; i < 4; ++i) {
                    const int m0 = mBase + q * 64 + i * 16 + fq * 4;
#pragma unroll
                    for (int r = 0; r < 4; ++r) {
                        float v = acc[q][i][j][r] + bias;
                        H[(size_t)(m0 + r) * NF + f] = f2bf(gelu_tanh(v));
                    }
                }
        }
    } else {
        // ---------------- conv mode: w2 [E][NF][DIM] f32 -> W2t [E][DIM][NF] bf16 ----------------
        float (*tA)[65] = (float(*)[65])smem;             // 64x65 f32 = 16640 B
        float (*tB)[65] = (float(*)[65])(smem + 16640);   // second sub-tile
        const int cid  = bid - bid / 5 - 1;               // 0..4095
        const int sub  = tid >> 8, stid = tid & 255;
        float (*tl)[65] = sub ? tB : tA;
        const int R = NF, C = DIM, tilesC = C >> 6, tilesR = R >> 6;
#pragma unroll
        for (int kk = 0; kk < 2; ++kk) {
            int ob = cid * 4 + sub * 2 + kk;              // old conv block id (0..16383)
            int tc = ob % tilesC; int bb = ob / tilesC;
            int tr = bb % tilesR; int e = bb / tilesR;
            const float* S = w2 + ((size_t)e * R + tr * 64) * C + tc * 64;
            const int rr = stid >> 4, cc = (stid & 15) * 4;
#pragma unroll
            for (int i = 0; i < 4; ++i) {
                float4 v = *(const float4*)(S + (size_t)(rr + i * 16) * C + cc);
                tl[rr + i * 16][cc + 0] = v.x; tl[rr + i * 16][cc + 1] = v.y;
                tl[rr + i * 16][cc + 2] = v.z; tl[rr + i * 16][cc + 3] = v.w;
            }
            __syncthreads();
            const int c = stid >> 2, r0 = (stid & 3) * 16;
            u16 tmp[16];
#pragma unroll
            for (int k2 = 0; k2 < 16; ++k2) tmp[k2] = f2bf(tl[r0 + k2][c]);
            u16* D = W2t + ((size_t)e * C + tc * 64 + c) * R + tr * 64 + r0;
            uint4 w0 = make_uint4((u32)tmp[0] | ((u32)tmp[1] << 16), (u32)tmp[2] | ((u32)tmp[3] << 16),
                                  (u32)tmp[4] | ((u32)tmp[5] << 16), (u32)tmp[6] | ((u32)tmp[7] << 16));
            uint4 w1 = make_uint4((u32)tmp[8] | ((u32)tmp[9] << 16), (u32)tmp[10] | ((u32)tmp[11] << 16),
                                  (u32)tmp[12] | ((u32)tmp[13] << 16), (u32)tmp[14] | ((u32)tmp[15] << 16));
            *(uint4*)(D) = w0;
            *(uint4*)(D + 8) = w1;
            __syncthreads();
        }
    }
}

// ---------- GEMM2: out[token] = gate * (H @ w2 + b2), scattered ----------
// 256x128 tile, BK=32, fine-phase schedule. 3 loads/tile (A2+B1),
// 4 LDS buffers (96 KB), counted vmcnt (6/3/0 tail). (unchanged from R4)
__global__ __launch_bounds__(512, 2) void moe_gemm2(const u16* __restrict__ H,
                                                    const u16* __restrict__ W2t,
                                                    const float* __restrict__ b2,
                                                    const int* __restrict__ tos,
                                                    const float* __restrict__ gp,
                                                    float* __restrict__ out) {
    __shared__ alignas(16) u16 Als[4][8192];   // 4 x (256 x 32) = 64 KB
    __shared__ alignas(16) u16 Bls[4][4096];   // 4 x (128 x 32) = 32 KB
    const int tid = threadIdx.x, wave = tid >> 6, lane = tid & 63;
    const int flat = blockIdx.x;            // 0..255
    const int xcd  = flat & 7;
    const int slot = flat >> 3;             // 0..31
    const int e    = xcd * 2 + (slot >> 4); // 2 experts per XCD
    const int tile = slot & 15;             // 0..15
    const int bm   = tile & 1;
    const int bn   = tile >> 1;             // 0..7
    const int r4   = lane >> 2;
    const int gch  = (lane & 3) ^ ((lane >> 3) & 3);
    const u16* aSrc = H + (size_t)(e * 512 + bm * 256 + wave * 16 + r4) * NF + gch * 8;
    const u16* bSrc = W2t + (size_t)e * DIM * NF
                    + (size_t)(bn * 128 + wave * 16 + r4) * NF + gch * 8;
    const int wm = wave & 1, wn = wave >> 1;
    const int fr = lane & 15, fq = lane >> 4;
    const int rdoff = fr * 32 + (fq ^ ((fr >> 1) & 3)) * 8;

    f32x4 acc[2][4][2] = {};

#define STG2A(P, T) do { const int ko = (T) * 32; u16* ad = &Als[P][wave * 512]; \
        gld16(aSrc + ko, ad); gld16(aSrc + (size_t)128 * NF + ko, ad + 4096); } while (0)
#define STG2B(P, T) do { const int ko = (T) * 32; u16* bd = &Bls[P][wave * 512]; \
        gld16(bSrc + ko, bd); } while (0)

    const int NT = NF / 32;                // 128 K-tiles
    STG2A(0, 0); STG2B(0, 0);
    STG2A(1, 1); STG2B(1, 1);
    STG2A(2, 2); STG2B(2, 2);
    for (int t = 0; t < NT; ++t) {
        const int c = t & 3;
        const int rem = NT - 1 - t;
        if (rem >= 2)      asm volatile("s_waitcnt vmcnt(6)" ::: "memory");
        else if (rem == 1) asm volatile("s_waitcnt vmcnt(3)" ::: "memory");
        else               asm volatile("s_waitcnt vmcnt(0)" ::: "memory");
        __builtin_amdgcn_sched_barrier(0);
        __builtin_amdgcn_s_barrier();
        __builtin_amdgcn_sched_barrier(0);
        const u16* Ab = &Als[c][0];
        const u16* Bb = &Bls[c][0];
        bf16x8 bF[2], aF[4];
        // ---- phase A ----
#pragma unroll
        for (int j = 0; j < 2; ++j)
            bF[j] = *(const bf16x8*)(const void*)(Bb + (wn * 32 + j * 16) * 32 + rdoff);
#pragma unroll
        for (int i = 0; i < 4; ++i)
            aF[i] = *(const bf16x8*)(const void*)(Ab + (wm * 128 + i * 16) * 32 + rdoff);
        if (t + 3 < NT) STG2A((c + 3) & 3, t + 3);
        __builtin_amdgcn_sched_barrier(0);
        asm volatile("s_waitcnt lgkmcnt(0)" ::: "memory");
        __builtin_amdgcn_sched_barrier(0);
        __builtin_amdgcn_s_setprio(1);
#pragma unroll
        for (int i = 0; i < 4; ++i)
#pragma unroll
            for (int j = 0; j < 2; ++j)
                acc[0][i][j] = __builtin_amdgcn_mfma_f32_16x16x32_bf16(aF[i], bF[j], acc[0][i][j], 0, 0, 0);
        __builtin_amdgcn_s_setprio(0);
        __builtin_amdgcn_sched_barrier(0);
        __builtin_amdgcn_s_barrier();
        __builtin_amdgcn_sched_barrier(0);
        // ---- phase B ----
#pragma unroll
        for (int i = 0; i < 4; ++i)
            aF[i] = *(const bf16x8*)(const void*)(Ab + (wm * 128 + 64 + i * 16) * 32 + rdoff);
        if (t + 3 < NT) STG2B((c + 3) & 3, t + 3);
        __builtin_amdgcn_sched_barrier(0);
        asm volatile("s_waitcnt lgkmcnt(0)" ::: "memory");
        __builtin_amdgcn_sched_barrier(0);
        __builtin_amdgcn_s_setprio(1);
#pragma unroll
        for (int i = 0; i < 4; ++i)
#pragma unroll
            for (int j = 0; j < 2; ++j)
                acc[1][i][j] = __builtin_amdgcn_mfma_f32_16x16x32_bf16(aF[i], bF[j], acc[1][i][j], 0, 0, 0);
        __builtin_amdgcn_s_setprio(0);
    }
#undef STG2A
#undef STG2B

    const int mBase = e * 512 + bm * 256 + wm * 128;
    const int nBase = bn * 128 + wn * 32;
#pragma unroll
    for (int q = 0; q < 2; ++q)
#pragma unroll
        for (int i = 0; i < 4; ++i) {
#pragma unroll
            for (int r = 0; r < 4; ++r) {
                const int m = mBase + q * 64 + i * 16 + fq * 4 + r;
                const int t = tos[m];
                if (t < 0) continue;
                const float g = gp[t];
#pragma unroll
                for (int j = 0; j < 2; ++j) {
                    const int d = nBase + j * 16 + fr;
                    out[(size_t)t * DIM + d] = g * (acc[q][i][j][r] + b2[e * DIM + d]);
                }
            }
        }
}

// ---------- launch ----------
extern "C" void kernel_launch(void* const* d_in, const int* in_sizes, int n_in,
                              void* d_out, int out_size, void* d_ws, size_t ws_size,
                              hipStream_t stream) {
    const float* x  = (const float*)d_in[0];
    const float* wg = (const float*)d_in[1];
    const float* w1 = (const float*)d_in[2];
    const float* b1 = (const float*)d_in[3];
    const float* w2 = (const float*)d_in[4];
    const float* b2 = (const float*)d_in[5];
    float* out = (float*)d_out;

    char* ws = (char*)d_ws;
    const size_t W1_OFF  = 0;                                    // 134,217,728 B
    const size_t W2_OFF  = W1_OFF + (size_t)NE * NF * DIM * 2;   // 134,217,728 B
    const size_t XG_OFF  = W2_OFF + (size_t)NE * NF * DIM * 2;   // 16,777,216 B
    const size_t H_OFF   = XG_OFF + (size_t)TOK * DIM * 2;       // 67,108,864 B
    const size_t SM_OFF  = H_OFF + (size_t)TOK * NF * 2;
    u16* W1bf = (u16*)(ws + W1_OFF);
    u16* W2bf = (u16*)(ws + W2_OFF);
    u16* Xg   = (u16*)(ws + XG_OFF);
    u16* H    = (u16*)(ws + H_OFF);
    int*   eidx = (int*)(ws + SM_OFF);                 // 32 KB
    float* gp   = (float*)(ws + SM_OFF + 32768);       // 32 KB
    int*   slot = (int*)(ws + SM_OFF + 65536);         // 32 KB
    int*   tos  = (int*)(ws + SM_OFF + 98304);         // 32 KB
    float* me   = (float*)(ws + SM_OFF + 131072);      // 64 B
    float* wgT  = (float*)(ws + SM_OFF + 131072 + 128);// 64 KB (16B aligned)

    float* tail = out + (size_t)TOK * DIM;             // [l_aux, exp_counts x16]

    moe_wgT<<<64, 256, 0, stream>>>(wg, wgT, me);
    moe_gate<<<TOK / 16, 256, 0, stream>>>(x, wgT, eidx, gp, me);
    moe_scan<<<1, 1024, 0, stream>>>(eidx, me, slot, tos, tail);
    moe_gather_zero<<<NE * CAP, 256, 0, stream>>>(x, tos, slot, Xg, out);
    moe_convT<<<NE * (DIM / 64) * (NF / 64), 256, 0, stream>>>(w1, W1bf, DIM, NF);
    moe_gemm1cv<<<5120, 512, 0, stream>>>(Xg, W1bf, b1, H, w2, W2bf);
    moe_gemm2<<<256, 512, 0, stream>>>(H, W2bf, b2, tos, gp, out);
}

// Round 6
// 808.527 us; speedup vs baseline: 1.1661x; 1.1004x over previous
//
#include <hip/hip_runtime.h>

typedef unsigned short u16;
typedef unsigned int   u32;
typedef unsigned long long u64;
typedef __attribute__((ext_vector_type(8))) __bf16 bf16x8;
typedef __attribute__((ext_vector_type(4))) float  f32x4;
typedef __attribute__((ext_vector_type(2))) u32    u32x2;

#define TOK 8192
#define DIM 1024
#define NE  16
#define NF  4096
#define CAP 512

// B LDS geometry (tr_b16 path): per K-tile buffer = 8 n_grps (16 cols each).
// n_grp = 4 fq-groups; fq-group = 8 k-rows x 32 B ([8][16] bf16 k-major) + 32 B pad
// = 288 B; n_grp stride = 4*288 + 32 = 1184 B (pads chosen so both the b128
// writes and the tr reads are <=2-way bank conflicts). Buffer = 8*1184 = 9472 B.
#define BQ  288
#define BG  1184
#define BLSZ 9472

// ---------- helpers ----------
__device__ __forceinline__ u16 f2bf(float f) {
    u32 u = __float_as_uint(f);
    u32 r = (u + 0x7FFFu + ((u >> 16) & 1u)) >> 16;   // RNE
    return (u16)r;
}

__device__ __forceinline__ float gelu_tanh(float x) {
    float u = 0.7978845608028654f * (x + 0.044715f * x * x * x);
    float t = __expf(-2.f * fabsf(u));
    float th = (1.f - t) / (1.f + t);
    th = (u < 0.f) ? -th : th;
    return 0.5f * x * (1.f + th);
}

__device__ __forceinline__ void gld16(const void* g, void* l) {
    __builtin_amdgcn_global_load_lds(
        (const __attribute__((address_space(1))) void*)g,
        (__attribute__((address_space(3))) void*)l, 16, 0, 0);
}

__device__ __forceinline__ u32 lds_addr(const void* p) {
    return (u32)(uintptr_t)(const __attribute__((address_space(3))) void*)p;
}

// 4x ds_read_b64_tr_b16 (two B-frags) + internal lgkmcnt(0) so the outputs are
// valid when the asm block retires (rule-18-safe).
#define BFRAG2(BF0, BF1, A0, A1) do { \
    u32x2 l0_, h0_, l1_, h1_; \
    asm volatile("ds_read_b64_tr_b16 %0, %4\n\t" \
                 "ds_read_b64_tr_b16 %1, %4 offset:128\n\t" \
                 "ds_read_b64_tr_b16 %2, %5\n\t" \
                 "ds_read_b64_tr_b16 %3, %5 offset:128\n\t" \
                 "s_waitcnt lgkmcnt(0)" \
                 : "=&v"(l0_), "=&v"(h0_), "=&v"(l1_), "=&v"(h1_) \
                 : "v"(A0), "v"(A1) : "memory"); \
    union { u32 u[4]; bf16x8 v; } c0_, c1_; \
    c0_.u[0] = l0_[0]; c0_.u[1] = l0_[1]; c0_.u[2] = h0_[0]; c0_.u[3] = h0_[1]; \
    c1_.u[0] = l1_[0]; c1_.u[1] = l1_[1]; c1_.u[2] = h1_[0]; c1_.u[3] = h1_[1]; \
    (BF0) = c0_.v; (BF1) = c1_.v; } while (0)

// ---------- small kernels ----------
__global__ void moe_wgT(const float* __restrict__ wg, float* __restrict__ wgT,
                        float* __restrict__ me_sums) {
    int i = blockIdx.x * 256 + threadIdx.x;     // 16384 elements
    if (i < NE) me_sums[i] = 0.f;
    int d = i >> 4, e = i & 15;
    wgT[(size_t)e * DIM + d] = wg[i];
}

// one thread per (token, expert); 256 thr = 16 tokens x 16 experts
__global__ void moe_gate(const float* __restrict__ x, const float* __restrict__ wgT,
                         int* __restrict__ eidx, float* __restrict__ gp,
                         float* __restrict__ me_sums) {
    __shared__ float lme[NE];
    const int tid = threadIdx.x;
    if (tid < NE) lme[tid] = 0.f;
    __syncthreads();
    const int tok = blockIdx.x * 16 + (tid >> 4);
    const int e   = tid & 15;
    const float4* xp = (const float4*)(x + (size_t)tok * DIM);
    const float4* wp = (const float4*)(wgT + (size_t)e * DIM);
    float acc = 0.f;
#pragma unroll 4
    for (int i = 0; i < DIM / 4; ++i) {
        float4 a = xp[i], b = wp[i];
        acc = fmaf(a.x, b.x, acc); acc = fmaf(a.y, b.y, acc);
        acc = fmaf(a.z, b.z, acc); acc = fmaf(a.w, b.w, acc);
    }
    float mx = acc;
    for (int off = 8; off; off >>= 1) mx = fmaxf(mx, __shfl_xor(mx, off, 16));
    float ex = __expf(acc - mx);
    float sum = ex;
    for (int off = 8; off; off >>= 1) sum += __shfl_xor(sum, off, 16);
    float p = ex / sum;
    atomicAdd(&lme[e], p);
    float bv = acc; int bi = e;
    for (int off = 8; off; off >>= 1) {
        float ov = __shfl_xor(bv, off, 16);
        int   oi = __shfl_xor(bi, off, 16);
        if (ov > bv || (ov == bv && oi < bi)) { bv = ov; bi = oi; }
    }
    float pw = __shfl(p, bi, 16);
    if (e == 0) { eidx[tok] = bi; gp[tok] = pw; }
    __syncthreads();
    if (tid < 16) atomicAdd(&me_sums[tid], lme[tid]);
}

// single block, 1024 threads: ordered cumsum slot assignment + counts + l_aux
__global__ void moe_scan(const int* __restrict__ eidx, const float* __restrict__ me_sums,
                         int* __restrict__ slot, int* __restrict__ tos,
                         float* __restrict__ tail /* d_out + TOK*DIM */) {
    __shared__ int wcnt[16][16];
    __shared__ int base[16];
    const int tid = threadIdx.x, wid = tid >> 6, lane = tid & 63;
    if (tid < 16) base[tid] = 0;
    for (int i = tid; i < NE * CAP; i += 1024) tos[i] = -1;
    __syncthreads();
    const u64 below = ((u64)1 << lane) - 1;
    for (int chunk = 0; chunk < TOK / 1024; ++chunk) {
        int t = chunk * 1024 + tid;
        int e = eidx[t];
        int rank = 0;
#pragma unroll
        for (int ex = 0; ex < 16; ++ex) {
            u64 m = __ballot(e == ex);
            if (e == ex)    rank = __popcll(m & below);
            if (lane == ex) wcnt[wid][ex] = __popcll(m);
        }
        __syncthreads();
        int pre = base[e];
        for (int w = 0; w < wid; ++w) pre += wcnt[w][e];
        int s = pre + rank;
        slot[t] = s;
        if (s < CAP) tos[e * CAP + s] = t;
        __syncthreads();
        if (tid < 16) {
            int tot = 0;
            for (int w = 0; w < 16; ++w) tot += wcnt[w][tid];
            base[tid] += tot;
        }
        __syncthreads();
    }
    if (tid == 0) {
        float laux = 0.f;
        for (int e2 = 0; e2 < 16; ++e2) {
            float me = me_sums[e2] / (float)TOK;
            float ce = (float)base[e2] / (float)TOK;
            laux += me * ce;
        }
        tail[0] = laux * (float)NE;
    }
    if (tid < 16) tail[1 + tid] = (float)base[tid];
}

// one block per slot row: gather x[token] -> bf16 Xg[slot]; also zero dropped tokens
__global__ void moe_gather_zero(const float* __restrict__ x, const int* __restrict__ tos,
                                const int* __restrict__ slot, u16* __restrict__ Xg,
                                float* __restrict__ out) {
    const int b = blockIdx.x, tid = threadIdx.x;
    const int t = tos[b];
    float4 v = make_float4(0.f, 0.f, 0.f, 0.f);
    if (t >= 0) v = *(const float4*)(x + (size_t)t * DIM + tid * 4);
    u32 lo = (u32)f2bf(v.x) | ((u32)f2bf(v.y) << 16);
    u32 hi = (u32)f2bf(v.z) | ((u32)f2bf(v.w) << 16);
    *(uint2*)(Xg + (size_t)b * DIM + tid * 4) = make_uint2(lo, hi);
    if (slot[b] >= CAP)
        *(float4*)(out + (size_t)b * DIM + tid * 4) = make_float4(0.f, 0.f, 0.f, 0.f);
}

// ---------- GEMM1: H = gelu(Xg @ w1 + b1), bf16 out; B read f32-direct ----------
// 256x128 tile, BK=32, 8 waves (2Mx4N). A: bf16 Xg via gld16 (XOR swizzle).
// B: w1 [e][k][n] f32 -> regs (2x dwordx4/thread) -> f2bf -> ds_write_b128 into
// tr-subtiled LDS -> consumed via ds_read_b64_tr_b16. 2-buffer, drain-per-tile.
__global__ __launch_bounds__(512, 4) void moe_gemm1(const u16* __restrict__ Xg,
                                                    const float* __restrict__ w1,
                                                    const float* __restrict__ b1,
                                                    u16* __restrict__ H) {
    __shared__ alignas(16) u16 Als[2][8192];     // 2 x (256m x 32k) = 32 KB
    __shared__ alignas(16) u16 Bls[2][BLSZ / 2]; // 2 x 9472 B
    const int tid = threadIdx.x, wave = tid >> 6, lane = tid & 63;
    const int flat = blockIdx.x;            // 0..1023
    const int xcd  = flat & 7;
    const int slot = flat >> 3;             // 0..127
    const int e    = xcd * 2 + (slot >> 6); // 2 experts per XCD
    const int tile = slot & 63;             // 0..63
    const int bm   = tile & 1;
    const int bn   = tile >> 1;             // 0..31
    const int r4   = lane >> 2;
    const int gch  = (lane & 3) ^ ((lane >> 3) & 3);
    const u16* aSrc = Xg + (size_t)(e * 512 + bm * 256 + wave * 16 + r4) * DIM + gch * 8;
    // B reg-stage source: thread t -> k = t>>4, n = (t&15)*8 (coalesced f32x8 per k-row)
    const int bk = tid >> 4, bn8 = tid & 15;
    const float* bSrc = w1 + ((size_t)e * DIM + bk) * NF + bn * 128 + bn8 * 8;
    // B LDS write offset (conflict-free by construction)
    const int bwoff = (bn8 >> 1) * BG + (bk >> 3) * BQ + (bk & 7) * 32 + (bn8 & 1) * 16;
    const int wm = wave & 1, wn = wave >> 1;
    const int fr = lane & 15, fq = lane >> 4;
    const int rdoff = fr * 32 + (fq ^ ((fr >> 1) & 3)) * 8;
    const u32 ldsB = lds_addr(&Bls[0][0]);
    const int btr0 = (wn * 2 + 0) * BG + fq * BQ + fr * 2;
    const int btr1 = (wn * 2 + 1) * BG + fq * BQ + fr * 2;

    f32x4 acc[2][4][2] = {};
    float4 q0, q1;

#define STGA1(P, T) do { const int ko = (T) * 32; \
        u16* ad = &Als[P][wave * 512]; \
        gld16(aSrc + ko, ad); gld16(aSrc + 128 * DIM + ko, ad + 4096); } while (0)
#define BWR1(P) do { \
        u32 p0 = (u32)f2bf(q0.x) | ((u32)f2bf(q0.y) << 16); \
        u32 p1 = (u32)f2bf(q0.z) | ((u32)f2bf(q0.w) << 16); \
        u32 p2 = (u32)f2bf(q1.x) | ((u32)f2bf(q1.y) << 16); \
        u32 p3 = (u32)f2bf(q1.z) | ((u32)f2bf(q1.w) << 16); \
        *(uint4*)((char*)&Bls[0][0] + (P) * BLSZ + bwoff) = make_uint4(p0, p1, p2, p3); } while (0)

    const int NT = DIM / 32;
    STGA1(0, 0);
    q0 = *(const float4*)(bSrc); q1 = *(const float4*)(bSrc + 4);
    asm volatile("s_waitcnt vmcnt(0)" ::: "memory");
    BWR1(0);
    asm volatile("s_waitcnt lgkmcnt(0)" ::: "memory");
    __builtin_amdgcn_s_barrier();
    for (int t = 0; t < NT; ++t) {
        const int buf = t & 1;
        if (t + 1 < NT) {
            STGA1(buf ^ 1, t + 1);
            const float* s = bSrc + (size_t)(t + 1) * (32 * NF);
            q0 = *(const float4*)(s); q1 = *(const float4*)(s + 4);
        }
        bf16x8 aF[4], bF[2];
        const u32 bb = ldsB + buf * BLSZ;
        BFRAG2(bF[0], bF[1], bb + btr0, bb + btr1);
        const u16* Ab = &Als[buf][0];
#pragma unroll
        for (int i = 0; i < 4; ++i)
            aF[i] = *(const bf16x8*)(const void*)(Ab + (wm * 128 + i * 16) * 32 + rdoff);
        __builtin_amdgcn_sched_barrier(0);
        __builtin_amdgcn_s_setprio(1);
#pragma unroll
        for (int i = 0; i < 4; ++i)
#pragma unroll
            for (int j = 0; j < 2; ++j)
                acc[0][i][j] = __builtin_amdgcn_mfma_f32_16x16x32_bf16(aF[i], bF[j], acc[0][i][j], 0, 0, 0);
        __builtin_amdgcn_s_setprio(0);
#pragma unroll
        for (int i = 0; i < 4; ++i)
            aF[i] = *(const bf16x8*)(const void*)(Ab + (wm * 128 + 64 + i * 16) * 32 + rdoff);
        __builtin_amdgcn_s_setprio(1);
#pragma unroll
        for (int i = 0; i < 4; ++i)
#pragma unroll
            for (int j = 0; j < 2; ++j)
                acc[1][i][j] = __builtin_amdgcn_mfma_f32_16x16x32_bf16(aF[i], bF[j], acc[1][i][j], 0, 0, 0);
        __builtin_amdgcn_s_setprio(0);
        if (t + 1 < NT) {
            asm volatile("s_waitcnt vmcnt(0)" ::: "memory");
            BWR1(buf ^ 1);
        }
        asm volatile("s_waitcnt lgkmcnt(0)" ::: "memory");
        __builtin_amdgcn_s_barrier();
    }
#undef STGA1
#undef BWR1

    const int mBase = e * 512 + bm * 256 + wm * 128;
    const int nBase = bn * 128 + wn * 32;
#pragma unroll
    for (int j = 0; j < 2; ++j) {
        const int f = nBase + j * 16 + fr;
        const float bias = b1[e * NF + f];
#pragma unroll
        for (int q = 0; q < 2; ++q)
#pragma unroll
            for (int i = 0; i < 4; ++i) {
                const int m0 = mBase + q * 64 + i * 16 + fq * 4;
#pragma unroll
                for (int r = 0; r < 4; ++r) {
                    float v = acc[q][i][j][r] + bias;
                    H[(size_t)(m0 + r) * NF + f] = f2bf(gelu_tanh(v));
                }
            }
    }
}

// ---------- GEMM2: out[token] = gate * (H @ w2 + b2); B = w2 f32-direct ----------
// Same structure as gemm1; K = NF (128 tiles), B row-stride DIM.
__global__ __launch_bounds__(512, 4) void moe_gemm2(const u16* __restrict__ H,
                                                    const float* __restrict__ w2,
                                                    const float* __restrict__ b2,
                                                    const int* __restrict__ tos,
                                                    const float* __restrict__ gp,
                                                    float* __restrict__ out) {
    __shared__ alignas(16) u16 Als[2][8192];
    __shared__ alignas(16) u16 Bls[2][BLSZ / 2];
    const int tid = threadIdx.x, wave = tid >> 6, lane = tid & 63;
    const int flat = blockIdx.x;            // 0..255
    const int xcd  = flat & 7;
    const int slot = flat >> 3;             // 0..31
    const int e    = xcd * 2 + (slot >> 4);
    const int tile = slot & 15;
    const int bm   = tile & 1;
    const int bn   = tile >> 1;             // 0..7
    const int r4   = lane >> 2;
    const int gch  = (lane & 3) ^ ((lane >> 3) & 3);
    const u16* aSrc = H + (size_t)(e * 512 + bm * 256 + wave * 16 + r4) * NF + gch * 8;
    const int bk = tid >> 4, bn8 = tid & 15;
    const float* bSrc = w2 + ((size_t)e * NF + bk) * DIM + bn * 128 + bn8 * 8;
    const int bwoff = (bn8 >> 1) * BG + (bk >> 3) * BQ + (bk & 7) * 32 + (bn8 & 1) * 16;
    const int wm = wave & 1, wn = wave >> 1;
    const int fr = lane & 15, fq = lane >> 4;
    const int rdoff = fr * 32 + (fq ^ ((fr >> 1) & 3)) * 8;
    const u32 ldsB = lds_addr(&Bls[0][0]);
    const int btr0 = (wn * 2 + 0) * BG + fq * BQ + fr * 2;
    const int btr1 = (wn * 2 + 1) * BG + fq * BQ + fr * 2;

    f32x4 acc[2][4][2] = {};
    float4 q0, q1;

#define STGA2(P, T) do { const int ko = (T) * 32; \
        u16* ad = &Als[P][wave * 512]; \
        gld16(aSrc + ko, ad); gld16(aSrc + (size_t)128 * NF + ko, ad + 4096); } while (0)
#define BWR2(P) do { \
        u32 p0 = (u32)f2bf(q0.x) | ((u32)f2bf(q0.y) << 16); \
        u32 p1 = (u32)f2bf(q0.z) | ((u32)f2bf(q0.w) << 16); \
        u32 p2 = (u32)f2bf(q1.x) | ((u32)f2bf(q1.y) << 16); \
        u32 p3 = (u32)f2bf(q1.z) | ((u32)f2bf(q1.w) << 16); \
        *(uint4*)((char*)&Bls[0][0] + (P) * BLSZ + bwoff) = make_uint4(p0, p1, p2, p3); } while (0)

    const int NT = NF / 32;
    STGA2(0, 0);
    q0 = *(const float4*)(bSrc); q1 = *(const float4*)(bSrc + 4);
    asm volatile("s_waitcnt vmcnt(0)" ::: "memory");
    BWR2(0);
    asm volatile("s_waitcnt lgkmcnt(0)" ::: "memory");
    __builtin_amdgcn_s_barrier();
    for (int t = 0; t < NT; ++t) {
        const int buf = t & 1;
        if (t + 1 < NT) {
            STGA2(buf ^ 1, t + 1);
            const float* s = bSrc + (size_t)(t + 1) * (32 * DIM);
            q0 = *(const float4*)(s); q1 = *(const float4*)(s + 4);
        }
        bf16x8 aF[4], bF[2];
        const u32 bb = ldsB + buf * BLSZ;
        BFRAG2(bF[0], bF[1], bb + btr0, bb + btr1);
        const u16* Ab = &Als[buf][0];
#pragma unroll
        for (int i = 0; i < 4; ++i)
            aF[i] = *(const bf16x8*)(const void*)(Ab + (wm * 128 + i * 16) * 32 + rdoff);
        __builtin_amdgcn_sched_barrier(0);
        __builtin_amdgcn_s_setprio(1);
#pragma unroll
        for (int i = 0; i < 4; ++i)
#pragma unroll
            for (int j = 0; j < 2; ++j)
                acc[0][i][j] = __builtin_amdgcn_mfma_f32_16x16x32_bf16(aF[i], bF[j], acc[0][i][j], 0, 0, 0);
        __builtin_amdgcn_s_setprio(0);
#pragma unroll
        for (int i = 0; i < 4; ++i)
            aF[i] = *(const bf16x8*)(const void*)(Ab + (wm * 128 + 64 + i * 16) * 32 + rdoff);
        __builtin_amdgcn_s_setprio(1);
#pragma unroll
        for (int i = 0; i < 4; ++i)
#pragma unroll
            for (int j = 0; j < 2; ++j)
                acc[1][i][j] = __builtin_amdgcn_mfma_f32_16x16x32_bf16(aF[i], bF[j], acc[1][i][j], 0, 0, 0);
        __builtin_amdgcn_s_setprio(0);
        if (t + 1 < NT) {
            asm volatile("s_waitcnt vmcnt(0)" ::: "memory");
            BWR2(buf ^ 1);
        }
        asm volatile("s_waitcnt lgkmcnt(0)" ::: "memory");
        __builtin_amdgcn_s_barrier();
    }
#undef STGA2
#undef BWR2

    const int mBase = e * 512 + bm * 256 + wm * 128;
    const int nBase = bn * 128 + wn * 32;
#pragma unroll
    for (int q = 0; q < 2; ++q)
#pragma unroll
        for (int i = 0; i < 4; ++i) {
#pragma unroll
            for (int r = 0; r < 4; ++r) {
                const int m = mBase + q * 64 + i * 16 + fq * 4 + r;
                const int t = tos[m];
                if (t < 0) continue;
                const float g = gp[t];
#pragma unroll
                for (int j = 0; j < 2; ++j) {
                    const int d = nBase + j * 16 + fr;
                    out[(size_t)t * DIM + d] = g * (acc[q][i][j][r] + b2[e * DIM + d]);
                }
            }
        }
}

// ---------- launch ----------
extern "C" void kernel_launch(void* const* d_in, const int* in_sizes, int n_in,
                              void* d_out, int out_size, void* d_ws, size_t ws_size,
                              hipStream_t stream) {
    const float* x  = (const float*)d_in[0];
    const float* wg = (const float*)d_in[1];
    const float* w1 = (const float*)d_in[2];
    const float* b1 = (const float*)d_in[3];
    const float* w2 = (const float*)d_in[4];
    const float* b2 = (const float*)d_in[5];
    float* out = (float*)d_out;

    char* ws = (char*)d_ws;
    const size_t XG_OFF = 0;                              // 16,777,216 B
    const size_t H_OFF  = XG_OFF + (size_t)TOK * DIM * 2; // 67,108,864 B
    const size_t SM_OFF = H_OFF + (size_t)TOK * NF * 2;
    u16* Xg = (u16*)(ws + XG_OFF);
    u16* H  = (u16*)(ws + H_OFF);
    int*   eidx = (int*)(ws + SM_OFF);                 // 32 KB
    float* gp   = (float*)(ws + SM_OFF + 32768);       // 32 KB
    int*   slot = (int*)(ws + SM_OFF + 65536);         // 32 KB
    int*   tos  = (int*)(ws + SM_OFF + 98304);         // 32 KB
    float* me   = (float*)(ws + SM_OFF + 131072);      // 64 B
    float* wgT  = (float*)(ws + SM_OFF + 131072 + 128);// 64 KB (16B aligned)

    float* tail = out + (size_t)TOK * DIM;             // [l_aux, exp_counts x16]

    moe_wgT<<<64, 256, 0, stream>>>(wg, wgT, me);
    moe_gate<<<TOK / 16, 256, 0, stream>>>(x, wgT, eidx, gp, me);
    moe_scan<<<1, 1024, 0, stream>>>(eidx, me, slot, tos, tail);
    moe_gather_zero<<<NE * CAP, 256, 0, stream>>>(x, tos, slot, Xg, out);
    moe_gemm1<<<1024, 512, 0, stream>>>(Xg, w1, b1, H);
    moe_gemm2<<<256, 512, 0, stream>>>(H, w2, b2, tos, gp, out);
}